// Round 10
// baseline (397.312 us; speedup 1.0000x reference)
//
#include <hip/hip_runtime.h>
#include <hip/hip_bf16.h>
#include <math.h>

typedef __bf16 bf16;
typedef __bf16 v8bf __attribute__((ext_vector_type(8)));
typedef __bf16 v4bf __attribute__((ext_vector_type(4)));
typedef float f32x4 __attribute__((ext_vector_type(4)));

#define L_SEQ 4096
#define DMODEL 1024
#define NHEADS 16
#define DH 64
#define NEG_BIG (-1e30f)
#define LN1E4_64 0.14391156f     // ln(10000)/64
#define QSCALE 0.18033688f       // (1/sqrt(64)) * log2(e)  -> exp2-domain scores

__device__ inline float fast_exp2(float x) { return __builtin_amdgcn_exp2f(x); }

// ---------------------------------------------------------------------------
// One-shot f32 -> bf16 conversion. xb[4096*1024], wqkvb[1536*1024], wob[1024*1024].
// ---------------------------------------------------------------------------
__global__ void convert_all(const float* __restrict__ x, const float* __restrict__ wq,
                            const float* __restrict__ wk, const float* __restrict__ wv,
                            const float* __restrict__ wo,
                            bf16* __restrict__ xb, bf16* __restrict__ wqkvb,
                            bf16* __restrict__ wob) {
    int i = (blockIdx.x * 256 + threadIdx.x) * 4;
    const float* src;
    bf16* dst;
    if (i < 4194304)      { src = x  + i;             dst = xb    + i; }
    else if (i < 5242880) { src = wq + (i - 4194304); dst = wqkvb + (i - 4194304); }
    else if (i < 5505024) { src = wk + (i - 5242880); dst = wqkvb + 1048576 + (i - 5242880); }
    else if (i < 5767168) { src = wv + (i - 5505024); dst = wqkvb + 1310720 + (i - 5505024); }
    else                  { src = wo + (i - 5767168); dst = wob   + (i - 5767168); }
    f32x4 v = *(const f32x4*)src;
    v4bf r;
#pragma unroll
    for (int j = 0; j < 4; j++) r[j] = (bf16)v[j];
    *(v4bf*)dst = r;
}

// ---------------------------------------------------------------------------
// Fused QKV projection + Q pre-scaled by QSCALE (exp2-domain).
// ---------------------------------------------------------------------------
__global__ __launch_bounds__(512) void gemm_qkv(const bf16* __restrict__ A,
                                                const bf16* __restrict__ W,
                                                bf16* __restrict__ Qb,
                                                bf16* __restrict__ Kb,
                                                bf16* __restrict__ Vtg,
                                                const int* __restrict__ tp) {
    __shared__ bf16 As[128][68];
    __shared__ bf16 Bs[128][68];
    const int K = 1024;
    const int tid = threadIdx.x;
    const int w = tid >> 6, lane = tid & 63;
    const int quad = lane >> 4, l16 = lane & 15;
    const int wm = (w & 1) * 64, wn = (w >> 1) * 32;
    const int bm = blockIdx.y * 128, bn = blockIdx.x * 128;

    f32x4 acc[4][2];
#pragma unroll
    for (int mf = 0; mf < 4; mf++)
#pragma unroll
        for (int nf = 0; nf < 2; nf++) acc[mf][nf] = (f32x4){0.f, 0.f, 0.f, 0.f};

    const int sr = tid >> 2;
    const int scb = (tid & 3) * 16;

    v8bf pa0, pa1, pb0, pb1;
    {
        const bf16* ap = &A[(size_t)(bm + sr) * K + scb];
        const bf16* bp = &W[(size_t)(bn + sr) * K + scb];
        pa0 = *(const v8bf*)ap; pa1 = *(const v8bf*)(ap + 8);
        pb0 = *(const v8bf*)bp; pb1 = *(const v8bf*)(bp + 8);
        *(v8bf*)&As[sr][scb] = pa0; *(v8bf*)&As[sr][scb + 8] = pa1;
        *(v8bf*)&Bs[sr][scb] = pb0; *(v8bf*)&Bs[sr][scb + 8] = pb1;
    }

    for (int kt = 0; kt < K; kt += 64) {
        __syncthreads();
        const bool more = (kt + 64) < K;
        if (more) {
            const bf16* ap = &A[(size_t)(bm + sr) * K + kt + 64 + scb];
            const bf16* bp = &W[(size_t)(bn + sr) * K + kt + 64 + scb];
            pa0 = *(const v8bf*)ap; pa1 = *(const v8bf*)(ap + 8);
            pb0 = *(const v8bf*)bp; pb1 = *(const v8bf*)(bp + 8);
        }
#pragma unroll
        for (int kf = 0; kf < 2; kf++) {
            v8bf a[4], b[2];
#pragma unroll
            for (int mf = 0; mf < 4; mf++) a[mf] = *(v8bf*)&As[wm + mf * 16 + l16][kf * 32 + quad * 8];
#pragma unroll
            for (int nf = 0; nf < 2; nf++) b[nf] = *(v8bf*)&Bs[wn + nf * 16 + l16][kf * 32 + quad * 8];
#pragma unroll
            for (int mf = 0; mf < 4; mf++)
#pragma unroll
                for (int nf = 0; nf < 2; nf++)
                    acc[mf][nf] = __builtin_amdgcn_mfma_f32_16x16x32_bf16(a[mf], b[nf], acc[mf][nf], 0, 0, 0);
        }
        __syncthreads();
        if (more) {
            *(v8bf*)&As[sr][scb] = pa0; *(v8bf*)&As[sr][scb + 8] = pa1;
            *(v8bf*)&Bs[sr][scb] = pb0; *(v8bf*)&Bs[sr][scb + 8] = pb1;
        }
    }

    if (bn < 1024) {          // ---- Q region: RoPE + QSCALE ----
#pragma unroll
        for (int mf = 0; mf < 4; mf++) {
            int pos_[4];
#pragma unroll
            for (int r = 0; r < 4; r++) pos_[r] = tp[bm + wm + mf * 16 + quad * 4 + r];
#pragma unroll
            for (int nf = 0; nf < 2; nf++) {
                const int col = bn + wn + nf * 16 + l16;
                float fr = __expf(-(float)((col & 63) & ~1) * LN1E4_64);
#pragma unroll
                for (int r = 0; r < 4; r++) {
                    float v = acc[mf][nf][r];
                    float sn, cs;
                    __sincosf((float)pos_[r] * fr, &sn, &cs);
                    float p = __shfl_xor(v, 1);
                    float res = (l16 & 1) ? (p * sn + v * cs) : (v * cs - p * sn);
                    int row = bm + wm + mf * 16 + quad * 4 + r;
                    Qb[(size_t)row * DMODEL + col] = (bf16)(res * QSCALE);
                }
            }
        }
    } else if (bn < 1280) {   // ---- K region: RoPE ----
#pragma unroll
        for (int mf = 0; mf < 4; mf++) {
            int pos_[4];
#pragma unroll
            for (int r = 0; r < 4; r++) pos_[r] = tp[bm + wm + mf * 16 + quad * 4 + r];
#pragma unroll
            for (int nf = 0; nf < 2; nf++) {
                const int kcol = bn - 1024 + wn + nf * 16 + l16;
                float fr = __expf(-(float)((kcol & 63) & ~1) * LN1E4_64);
#pragma unroll
                for (int r = 0; r < 4; r++) {
                    float v = acc[mf][nf][r];
                    float sn, cs;
                    __sincosf((float)pos_[r] * fr, &sn, &cs);
                    float p = __shfl_xor(v, 1);
                    float res = (l16 & 1) ? (p * sn + v * cs) : (v * cs - p * sn);
                    int row = bm + wm + mf * 16 + quad * 4 + r;
                    Kb[(size_t)row * 256 + kcol] = (bf16)res;
                }
            }
        }
    } else {                  // ---- V region: transposed store ----
#pragma unroll
        for (int mf = 0; mf < 4; mf++)
#pragma unroll
            for (int nf = 0; nf < 2; nf++) {
                v4bf pk;
#pragma unroll
                for (int r = 0; r < 4; r++) pk[r] = (bf16)acc[mf][nf][r];
                int vcol = bn - 1280 + wn + nf * 16 + l16;
                int row = bm + wm + mf * 16 + quad * 4;
                *(v4bf*)&Vtg[(size_t)vcol * L_SEQ + row] = pk;
            }
    }
}

// ---------------------------------------------------------------------------
// Output projection.
// ---------------------------------------------------------------------------
__global__ __launch_bounds__(512) void gemm_out(const bf16* __restrict__ A,
                                                const bf16* __restrict__ W,
                                                float* __restrict__ C) {
    __shared__ bf16 As[128][68];
    __shared__ bf16 Bs[128][68];
    const int K = 1024, N = 1024;
    const int tid = threadIdx.x;
    const int w = tid >> 6, lane = tid & 63;
    const int quad = lane >> 4, l16 = lane & 15;
    const int wm = (w & 1) * 64, wn = (w >> 1) * 32;
    const int bm = blockIdx.y * 128, bn = blockIdx.x * 128;

    f32x4 acc[4][2];
#pragma unroll
    for (int mf = 0; mf < 4; mf++)
#pragma unroll
        for (int nf = 0; nf < 2; nf++) acc[mf][nf] = (f32x4){0.f, 0.f, 0.f, 0.f};

    const int sr = tid >> 2;
    const int scb = (tid & 3) * 16;

    v8bf pa0, pa1, pb0, pb1;
    {
        const bf16* ap = &A[(size_t)(bm + sr) * K + scb];
        const bf16* bp = &W[(size_t)(bn + sr) * K + scb];
        pa0 = *(const v8bf*)ap; pa1 = *(const v8bf*)(ap + 8);
        pb0 = *(const v8bf*)bp; pb1 = *(const v8bf*)(bp + 8);
        *(v8bf*)&As[sr][scb] = pa0; *(v8bf*)&As[sr][scb + 8] = pa1;
        *(v8bf*)&Bs[sr][scb] = pb0; *(v8bf*)&Bs[sr][scb + 8] = pb1;
    }

    for (int kt = 0; kt < K; kt += 64) {
        __syncthreads();
        const bool more = (kt + 64) < K;
        if (more) {
            const bf16* ap = &A[(size_t)(bm + sr) * K + kt + 64 + scb];
            const bf16* bp = &W[(size_t)(bn + sr) * K + kt + 64 + scb];
            pa0 = *(const v8bf*)ap; pa1 = *(const v8bf*)(ap + 8);
            pb0 = *(const v8bf*)bp; pb1 = *(const v8bf*)(bp + 8);
        }
#pragma unroll
        for (int kf = 0; kf < 2; kf++) {
            v8bf a[4], b[2];
#pragma unroll
            for (int mf = 0; mf < 4; mf++) a[mf] = *(v8bf*)&As[wm + mf * 16 + l16][kf * 32 + quad * 8];
#pragma unroll
            for (int nf = 0; nf < 2; nf++) b[nf] = *(v8bf*)&Bs[wn + nf * 16 + l16][kf * 32 + quad * 8];
#pragma unroll
            for (int mf = 0; mf < 4; mf++)
#pragma unroll
                for (int nf = 0; nf < 2; nf++)
                    acc[mf][nf] = __builtin_amdgcn_mfma_f32_16x16x32_bf16(a[mf], b[nf], acc[mf][nf], 0, 0, 0);
        }
        __syncthreads();
        if (more) {
            *(v8bf*)&As[sr][scb] = pa0; *(v8bf*)&As[sr][scb + 8] = pa1;
            *(v8bf*)&Bs[sr][scb] = pb0; *(v8bf*)&Bs[sr][scb + 8] = pb1;
        }
    }
#pragma unroll
    for (int mf = 0; mf < 4; mf++)
#pragma unroll
        for (int nf = 0; nf < 2; nf++)
#pragma unroll
            for (int r = 0; r < 4; r++) {
                int row = bm + wm + mf * 16 + quad * 4 + r;
                int col = bn + wn + nf * 16 + l16;
                C[(size_t)row * N + col] = acc[mf][nf][r];
            }
}

// ---------------------------------------------------------------------------
// Flash v6: 4-way split-K, exact leveling, P aliased onto K (LDS ~34 KB ->
// 4 blocks/CU), exp2-domain softmax (Q pre-scaled). Grid (64, 16).
// Block bx = 2q+i handles (qb=q, part i) and (qb=31-q, part 3-i);
// part j of [0,T) = [j*T/4, (j+1)*T/4). Every block ~8.25 tiles.
// ---------------------------------------------------------------------------
__global__ __launch_bounds__(256, 4) void flash6(const bf16* __restrict__ Q,
                                                 const bf16* __restrict__ Kb,
                                                 const bf16* __restrict__ Vtg,
                                                 bf16* __restrict__ O0,
                                                 bf16* __restrict__ O1,
                                                 bf16* __restrict__ O2,
                                                 bf16* __restrict__ O3,
                                                 float* __restrict__ ML) {
    __shared__ bf16 KsPs[128][68];   // K tile; rows reused as P tile
    __shared__ bf16 Vt[64][132];
    const int h = blockIdx.y, kvh = h >> 2;
    const int bx = blockIdx.x;
    const int tid = threadIdx.x;
    const int w = tid >> 6, lane = tid & 63;
    const int quad = lane >> 4, l16 = lane & 15;
    const int krow = tid >> 1, kcb = (tid & 1) * 32;
    const int vr = tid >> 2, vcb = (tid & 3) * 32;
    bf16* const Ops[4] = {O0, O1, O2, O3};

    const int q0 = bx >> 1, i0 = bx & 1;

    for (int p = 0; p < 2; p++) {
        const int qb = p ? (31 - q0) : q0;
        const int j  = p ? (3 - i0) : i0;
        const int T = qb + 1;
        const int k0 = (j * T) >> 2;
        const int k1 = ((j + 1) * T) >> 2;
        bf16* Op = Ops[j];
        float* mlp = ML + (size_t)(j * NHEADS + h) * L_SEQ * 2;

        if (k0 >= k1) {   // empty piece: zero partial (block-uniform)
            for (int idx = tid; idx < 128 * 64; idx += 256) {
                int rr = idx >> 6, cc = idx & 63;
                Op[(size_t)(qb * 128 + rr) * DMODEL + h * DH + cc] = (bf16)0.f;
            }
            if (tid < 128) {
                mlp[(qb * 128 + tid) * 2 + 0] = NEG_BIG;
                mlp[(qb * 128 + tid) * 2 + 1] = 0.f;
            }
            continue;
        }

        v8bf qf[2][2];
#pragma unroll
        for (int mf = 0; mf < 2; mf++)
#pragma unroll
            for (int kf = 0; kf < 2; kf++)
                qf[mf][kf] = *(const v8bf*)&Q[(size_t)(qb * 128 + w * 32 + mf * 16 + l16) * DMODEL
                                              + h * DH + kf * 32 + quad * 8];

        f32x4 oacc[2][4];
#pragma unroll
        for (int mf = 0; mf < 2; mf++)
#pragma unroll
            for (int d = 0; d < 4; d++) oacc[mf][d] = (f32x4){0.f, 0.f, 0.f, 0.f};
        float m_i[2][4], l_i[2][4];
#pragma unroll
        for (int mf = 0; mf < 2; mf++)
#pragma unroll
            for (int r = 0; r < 4; r++) { m_i[mf][r] = NEG_BIG; l_i[mf][r] = 0.f; }

        v8bf kreg[4], vreg[4];
        {   // stage first tile of this piece
            const bf16* ks = &Kb[(size_t)(k0 * 128 + krow) * 256 + kvh * DH + kcb];
            const bf16* vs = &Vtg[(size_t)(kvh * DH + vr) * L_SEQ + k0 * 128 + vcb];
#pragma unroll
            for (int u = 0; u < 4; u++) { kreg[u] = *(const v8bf*)&ks[8 * u]; vreg[u] = *(const v8bf*)&vs[8 * u]; }
            __syncthreads();   // prior piece's LDS reads complete
#pragma unroll
            for (int u = 0; u < 4; u++) { *(v8bf*)&KsPs[krow][kcb + 8 * u] = kreg[u]; *(v8bf*)&Vt[vr][vcb + 8 * u] = vreg[u]; }
        }

        for (int kb = k0; kb < k1; kb++) {
            __syncthreads();   // staged tile visible
            if (kb + 1 < k1) {
                const bf16* ks = &Kb[(size_t)((kb + 1) * 128 + krow) * 256 + kvh * DH + kcb];
                const bf16* vs = &Vtg[(size_t)(kvh * DH + vr) * L_SEQ + (kb + 1) * 128 + vcb];
#pragma unroll
                for (int u = 0; u < 4; u++) { kreg[u] = *(const v8bf*)&ks[8 * u]; vreg[u] = *(const v8bf*)&vs[8 * u]; }
            }

            // ---- S = Q K^T (exp2-domain; scale pre-folded into Q)
            f32x4 s[2][8];
#pragma unroll
            for (int n = 0; n < 8; n++) {
                v8bf b0 = *(v8bf*)&KsPs[n * 16 + l16][quad * 8];
                v8bf b1 = *(v8bf*)&KsPs[n * 16 + l16][32 + quad * 8];
#pragma unroll
                for (int mf = 0; mf < 2; mf++) {
                    s[mf][n] = (f32x4){0.f, 0.f, 0.f, 0.f};
                    s[mf][n] = __builtin_amdgcn_mfma_f32_16x16x32_bf16(qf[mf][0], b0, s[mf][n], 0, 0, 0);
                    s[mf][n] = __builtin_amdgcn_mfma_f32_16x16x32_bf16(qf[mf][1], b1, s[mf][n], 0, 0, 0);
                }
            }

            if (kb == qb) {   // causal mask (diagonal tile only)
#pragma unroll
                for (int mf = 0; mf < 2; mf++) {
                    int rbase = qb * 128 + w * 32 + mf * 16 + quad * 4;
#pragma unroll
                    for (int n = 0; n < 8; n++) {
                        int colg = kb * 128 + n * 16 + l16;
#pragma unroll
                        for (int r = 0; r < 4; r++)
                            s[mf][n][r] = (colg <= rbase + r) ? s[mf][n][r] : NEG_BIG;
                    }
                }
            }

            // ---- online softmax (exp2 domain)
            float mx[2][4];
#pragma unroll
            for (int mf = 0; mf < 2; mf++)
#pragma unroll
                for (int r = 0; r < 4; r++) {
                    float m0 = s[mf][0][r];
#pragma unroll
                    for (int n = 1; n < 8; n++) m0 = fmaxf(m0, s[mf][n][r]);
                    mx[mf][r] = m0;
                }
#pragma unroll
            for (int off = 1; off < 16; off <<= 1)
#pragma unroll
                for (int mf = 0; mf < 2; mf++)
#pragma unroll
                    for (int r = 0; r < 4; r++)
                        mx[mf][r] = fmaxf(mx[mf][r], __shfl_xor(mx[mf][r], off));

            float alpha[2][4], mnew[2][4], rs[2][4];
#pragma unroll
            for (int mf = 0; mf < 2; mf++)
#pragma unroll
                for (int r = 0; r < 4; r++) {
                    mnew[mf][r]  = fmaxf(m_i[mf][r], mx[mf][r]);
                    alpha[mf][r] = fast_exp2(m_i[mf][r] - mnew[mf][r]);
                    rs[mf][r] = 0.f;
                }
#pragma unroll
            for (int mf = 0; mf < 2; mf++)
#pragma unroll
                for (int n = 0; n < 8; n++)
#pragma unroll
                    for (int r = 0; r < 4; r++) {
                        float pv = fast_exp2(s[mf][n][r] - mnew[mf][r]);
                        s[mf][n][r] = pv;
                        rs[mf][r] += pv;
                    }
#pragma unroll
            for (int off = 1; off < 16; off <<= 1)
#pragma unroll
                for (int mf = 0; mf < 2; mf++)
#pragma unroll
                    for (int r = 0; r < 4; r++) rs[mf][r] += __shfl_xor(rs[mf][r], off);
#pragma unroll
            for (int mf = 0; mf < 2; mf++)
#pragma unroll
                for (int r = 0; r < 4; r++) {
                    l_i[mf][r] = l_i[mf][r] * alpha[mf][r] + rs[mf][r];
                    m_i[mf][r] = mnew[mf][r];
                }
#pragma unroll
            for (int mf = 0; mf < 2; mf++)
#pragma unroll
                for (int d = 0; d < 4; d++)
#pragma unroll
                    for (int r = 0; r < 4; r++) oacc[mf][d][r] *= alpha[mf][r];

            __syncthreads();   // all K reads drained -> safe to overwrite with P

            // ---- PV in two 64-key halves; P rows [w*32,+32) wave-private
#pragma unroll
            for (int half = 0; half < 2; half++) {
#pragma unroll
                for (int mf = 0; mf < 2; mf++)
#pragma unroll
                    for (int n = 0; n < 4; n++)
#pragma unroll
                        for (int r = 0; r < 4; r++)
                            KsPs[w * 32 + mf * 16 + quad * 4 + r][n * 16 + l16] =
                                (bf16)s[mf][half * 4 + n][r];
#pragma unroll
                for (int kf = 0; kf < 2; kf++) {
#pragma unroll
                    for (int mf = 0; mf < 2; mf++) {
                        v8bf pa = *(v8bf*)&KsPs[w * 32 + mf * 16 + l16][kf * 32 + quad * 8];
#pragma unroll
                        for (int d = 0; d < 4; d++) {
                            v8bf vb = *(v8bf*)&Vt[d * 16 + l16][half * 64 + kf * 32 + quad * 8];
                            oacc[mf][d] = __builtin_amdgcn_mfma_f32_16x16x32_bf16(pa, vb, oacc[mf][d], 0, 0, 0);
                        }
                    }
                }
            }

            __syncthreads();   // P/V reads done -> safe to restage next tile
            if (kb + 1 < k1) {
#pragma unroll
                for (int u = 0; u < 4; u++) { *(v8bf*)&KsPs[krow][kcb + 8 * u] = kreg[u]; *(v8bf*)&Vt[vr][vcb + 8 * u] = vreg[u]; }
            }
        }

        // ---- unnormalized partial write
#pragma unroll
        for (int mf = 0; mf < 2; mf++)
#pragma unroll
            for (int d = 0; d < 4; d++)
#pragma unroll
                for (int r = 0; r < 4; r++) {
                    int row = qb * 128 + w * 32 + mf * 16 + quad * 4 + r;
                    Op[(size_t)row * DMODEL + h * DH + d * 16 + l16] = (bf16)oacc[mf][d][r];
                }
        if (l16 == 0) {
#pragma unroll
            for (int mf = 0; mf < 2; mf++)
#pragma unroll
                for (int r = 0; r < 4; r++) {
                    int row = qb * 128 + w * 32 + mf * 16 + quad * 4 + r;
                    mlp[row * 2 + 0] = m_i[mf][r];
                    mlp[row * 2 + 1] = l_i[mf][r];
                }
        }
    }
}

// ---------------------------------------------------------------------------
// Combine 4 split-K partials into normalized Attn (bf16). exp2 domain.
// ---------------------------------------------------------------------------
__global__ void combine4(const bf16* __restrict__ O0, const bf16* __restrict__ O1,
                         const bf16* __restrict__ O2, const bf16* __restrict__ O3,
                         const float* __restrict__ ML, bf16* __restrict__ Attn) {
    int gid = blockIdx.x * 256 + threadIdx.x;
    int row = gid >> 8;
    int cg = (gid & 255) * 4;
    int h = cg >> 6;
    float m[4], l[4];
#pragma unroll
    for (int j = 0; j < 4; j++) {
        const float* ml = ML + (((size_t)(j * NHEADS + h) * L_SEQ) + row) * 2;
        m[j] = ml[0]; l[j] = ml[1];
    }
    float mmax = fmaxf(fmaxf(m[0], m[1]), fmaxf(m[2], m[3]));
    float a[4], denom = 0.f;
#pragma unroll
    for (int j = 0; j < 4; j++) { a[j] = fast_exp2(m[j] - mmax); denom += a[j] * l[j]; }
    float inv = 1.f / denom;
    v4bf o0 = *(const v4bf*)&O0[(size_t)row * DMODEL + cg];
    v4bf o1 = *(const v4bf*)&O1[(size_t)row * DMODEL + cg];
    v4bf o2 = *(const v4bf*)&O2[(size_t)row * DMODEL + cg];
    v4bf o3 = *(const v4bf*)&O3[(size_t)row * DMODEL + cg];
    v4bf res;
#pragma unroll
    for (int jj = 0; jj < 4; jj++)
        res[jj] = (bf16)((a[0] * (float)o0[jj] + a[1] * (float)o1[jj] +
                          a[2] * (float)o2[jj] + a[3] * (float)o3[jj]) * inv);
    *(v4bf*)&Attn[(size_t)row * DMODEL + cg] = res;
}

// ---------------------------------------------------------------------------
extern "C" void kernel_launch(void* const* d_in, const int* in_sizes, int n_in,
                              void* d_out, int out_size, void* d_ws, size_t ws_size,
                              hipStream_t stream) {
    const float* x  = (const float*)d_in[0];
    const float* Wq = (const float*)d_in[1];
    const float* Wk = (const float*)d_in[2];
    const float* Wv = (const float*)d_in[3];
    const float* Wo = (const float*)d_in[4];
    const int*   tp = (const int*)d_in[5];
    float* out = (float*)d_out;

    bf16*  xb    = (bf16*)d_ws;               // 4,194,304 (reused as Attn)
    bf16*  wqkvb = xb    + 4194304;           // 1,572,864
    bf16*  wob   = wqkvb + 1572864;           // 1,048,576
    bf16*  Qb    = wob   + 1048576;           // 4,194,304
    bf16*  Kb    = Qb    + 4194304;           // 1,048,576  [4096][256]
    bf16*  Vtg   = Kb    + 1048576;           // 1,048,576  [256][4096]
    bf16*  O2    = Vtg   + 1048576;           // 4,194,304 partial j=2
    bf16*  O3    = O2    + 4194304;           // 4,194,304 partial j=3
    float* MLf   = (float*)(O3 + 4194304);    // 4*16*4096*2 = 524,288 f32
    bf16*  Attn  = xb;
    bf16*  O0    = (bf16*)d_out;              // partial j=0 (in f32 out buffer)
    bf16*  O1    = O0 + 4194304;              // partial j=1

    convert_all<<<6656, 256, 0, stream>>>(x, Wq, Wk, Wv, Wo, xb, wqkvb, wob);
    gemm_qkv<<<dim3(12, 32), 512, 0, stream>>>(xb, wqkvb, Qb, Kb, Vtg, tp);
    flash6<<<dim3(64, NHEADS), 256, 0, stream>>>(Qb, Kb, Vtg, O0, O1, O2, O3, MLf);
    combine4<<<4096, 256, 0, stream>>>(O0, O1, O2, O3, MLf, Attn);
    gemm_out<<<dim3(8, 32), 512, 0, stream>>>(Attn, wob, out);
}

// Round 11
// 307.628 us; speedup vs baseline: 1.2915x; 1.2915x over previous
//
#include <hip/hip_runtime.h>
#include <hip/hip_bf16.h>
#include <math.h>

typedef __bf16 bf16;
typedef __bf16 v8bf __attribute__((ext_vector_type(8)));
typedef __bf16 v4bf __attribute__((ext_vector_type(4)));
typedef float f32x4 __attribute__((ext_vector_type(4)));

#define L_SEQ 4096
#define DMODEL 1024
#define NHEADS 16
#define DH 64
#define NEG_BIG (-1e30f)
#define LN1E4_64 0.14391156f     // ln(10000)/64
#define QSCALE 0.18033688f       // (1/sqrt(64)) * log2(e)  -> exp2-domain scores

__device__ inline float fast_exp2(float x) { return __builtin_amdgcn_exp2f(x); }

// ---------------------------------------------------------------------------
// One-shot f32 -> bf16 conversion. xb[4096*1024], wqkvb[1536*1024], wob[1024*1024].
// ---------------------------------------------------------------------------
__global__ void convert_all(const float* __restrict__ x, const float* __restrict__ wq,
                            const float* __restrict__ wk, const float* __restrict__ wv,
                            const float* __restrict__ wo,
                            bf16* __restrict__ xb, bf16* __restrict__ wqkvb,
                            bf16* __restrict__ wob) {
    int i = (blockIdx.x * 256 + threadIdx.x) * 4;
    const float* src;
    bf16* dst;
    if (i < 4194304)      { src = x  + i;             dst = xb    + i; }
    else if (i < 5242880) { src = wq + (i - 4194304); dst = wqkvb + (i - 4194304); }
    else if (i < 5505024) { src = wk + (i - 5242880); dst = wqkvb + 1048576 + (i - 5242880); }
    else if (i < 5767168) { src = wv + (i - 5505024); dst = wqkvb + 1310720 + (i - 5505024); }
    else                  { src = wo + (i - 5767168); dst = wob   + (i - 5767168); }
    f32x4 v = *(const f32x4*)src;
    v4bf r;
#pragma unroll
    for (int j = 0; j < 4; j++) r[j] = (bf16)v[j];
    *(v4bf*)dst = r;
}

// ---------------------------------------------------------------------------
// Fused QKV projection: 128x64 tiles, 256 threads (4 waves), reg prefetch.
// Grid (24, 32) = 768 blocks -> 3 blocks/CU. Q pre-scaled by QSCALE.
// ---------------------------------------------------------------------------
__global__ __launch_bounds__(256) void gemm_qkv(const bf16* __restrict__ A,
                                                const bf16* __restrict__ W,
                                                bf16* __restrict__ Qb,
                                                bf16* __restrict__ Kb,
                                                bf16* __restrict__ Vtg,
                                                const int* __restrict__ tp) {
    __shared__ bf16 As[128][68];
    __shared__ bf16 Bs[64][68];
    const int K = 1024;
    const int tid = threadIdx.x;
    const int w = tid >> 6, lane = tid & 63;
    const int quad = lane >> 4, l16 = lane & 15;
    const int wm = (w & 1) * 64, wn = (w >> 1) * 32;
    const int bm = blockIdx.y * 128, bn = blockIdx.x * 64;

    f32x4 acc[4][2];
#pragma unroll
    for (int mf = 0; mf < 4; mf++)
#pragma unroll
        for (int nf = 0; nf < 2; nf++) acc[mf][nf] = (f32x4){0.f, 0.f, 0.f, 0.f};

    const int ar = tid >> 1, acb = (tid & 1) * 32;   // A: 128 rows x 64 cols
    const int br = tid >> 2, bcb = (tid & 3) * 16;   // B: 64 rows x 64 cols

    v8bf pa[4], pb[2];
    {
        const bf16* ap = &A[(size_t)(bm + ar) * K + acb];
        const bf16* bp = &W[(size_t)(bn + br) * K + bcb];
#pragma unroll
        for (int u = 0; u < 4; u++) pa[u] = *(const v8bf*)&ap[8 * u];
#pragma unroll
        for (int u = 0; u < 2; u++) pb[u] = *(const v8bf*)&bp[8 * u];
#pragma unroll
        for (int u = 0; u < 4; u++) *(v8bf*)&As[ar][acb + 8 * u] = pa[u];
#pragma unroll
        for (int u = 0; u < 2; u++) *(v8bf*)&Bs[br][bcb + 8 * u] = pb[u];
    }

    for (int kt = 0; kt < K; kt += 64) {
        __syncthreads();
        const bool more = (kt + 64) < K;
        if (more) {
            const bf16* ap = &A[(size_t)(bm + ar) * K + kt + 64 + acb];
            const bf16* bp = &W[(size_t)(bn + br) * K + kt + 64 + bcb];
#pragma unroll
            for (int u = 0; u < 4; u++) pa[u] = *(const v8bf*)&ap[8 * u];
#pragma unroll
            for (int u = 0; u < 2; u++) pb[u] = *(const v8bf*)&bp[8 * u];
        }
#pragma unroll
        for (int kf = 0; kf < 2; kf++) {
            v8bf a[4], b[2];
#pragma unroll
            for (int mf = 0; mf < 4; mf++) a[mf] = *(v8bf*)&As[wm + mf * 16 + l16][kf * 32 + quad * 8];
#pragma unroll
            for (int nf = 0; nf < 2; nf++) b[nf] = *(v8bf*)&Bs[wn + nf * 16 + l16][kf * 32 + quad * 8];
#pragma unroll
            for (int mf = 0; mf < 4; mf++)
#pragma unroll
                for (int nf = 0; nf < 2; nf++)
                    acc[mf][nf] = __builtin_amdgcn_mfma_f32_16x16x32_bf16(a[mf], b[nf], acc[mf][nf], 0, 0, 0);
        }
        __syncthreads();
        if (more) {
#pragma unroll
            for (int u = 0; u < 4; u++) *(v8bf*)&As[ar][acb + 8 * u] = pa[u];
#pragma unroll
            for (int u = 0; u < 2; u++) *(v8bf*)&Bs[br][bcb + 8 * u] = pb[u];
        }
    }

    if (bn < 1024) {          // ---- Q region: RoPE + QSCALE ----
#pragma unroll
        for (int mf = 0; mf < 4; mf++) {
            int pos_[4];
#pragma unroll
            for (int r = 0; r < 4; r++) pos_[r] = tp[bm + wm + mf * 16 + quad * 4 + r];
#pragma unroll
            for (int nf = 0; nf < 2; nf++) {
                const int col = bn + wn + nf * 16 + l16;
                float fr = __expf(-(float)((col & 63) & ~1) * LN1E4_64);
#pragma unroll
                for (int r = 0; r < 4; r++) {
                    float v = acc[mf][nf][r];
                    float sn, cs;
                    __sincosf((float)pos_[r] * fr, &sn, &cs);
                    float p = __shfl_xor(v, 1);
                    float res = (l16 & 1) ? (p * sn + v * cs) : (v * cs - p * sn);
                    int row = bm + wm + mf * 16 + quad * 4 + r;
                    Qb[(size_t)row * DMODEL + col] = (bf16)(res * QSCALE);
                }
            }
        }
    } else if (bn < 1280) {   // ---- K region: RoPE ----
#pragma unroll
        for (int mf = 0; mf < 4; mf++) {
            int pos_[4];
#pragma unroll
            for (int r = 0; r < 4; r++) pos_[r] = tp[bm + wm + mf * 16 + quad * 4 + r];
#pragma unroll
            for (int nf = 0; nf < 2; nf++) {
                const int kcol = bn - 1024 + wn + nf * 16 + l16;
                float fr = __expf(-(float)((kcol & 63) & ~1) * LN1E4_64);
#pragma unroll
                for (int r = 0; r < 4; r++) {
                    float v = acc[mf][nf][r];
                    float sn, cs;
                    __sincosf((float)pos_[r] * fr, &sn, &cs);
                    float p = __shfl_xor(v, 1);
                    float res = (l16 & 1) ? (p * sn + v * cs) : (v * cs - p * sn);
                    int row = bm + wm + mf * 16 + quad * 4 + r;
                    Kb[(size_t)row * 256 + kcol] = (bf16)res;
                }
            }
        }
    } else {                  // ---- V region: transposed store ----
#pragma unroll
        for (int mf = 0; mf < 4; mf++)
#pragma unroll
            for (int nf = 0; nf < 2; nf++) {
                v4bf pk;
#pragma unroll
                for (int r = 0; r < 4; r++) pk[r] = (bf16)acc[mf][nf][r];
                int vcol = bn - 1280 + wn + nf * 16 + l16;
                int row = bm + wm + mf * 16 + quad * 4;
                *(v4bf*)&Vtg[(size_t)vcol * L_SEQ + row] = pk;
            }
    }
}

// ---------------------------------------------------------------------------
// Output projection: 128x64 tiles, 256 threads. Grid (16, 32) = 512 blocks.
// ---------------------------------------------------------------------------
__global__ __launch_bounds__(256) void gemm_out(const bf16* __restrict__ A,
                                                const bf16* __restrict__ W,
                                                float* __restrict__ C) {
    __shared__ bf16 As[128][68];
    __shared__ bf16 Bs[64][68];
    const int K = 1024, N = 1024;
    const int tid = threadIdx.x;
    const int w = tid >> 6, lane = tid & 63;
    const int quad = lane >> 4, l16 = lane & 15;
    const int wm = (w & 1) * 64, wn = (w >> 1) * 32;
    const int bm = blockIdx.y * 128, bn = blockIdx.x * 64;

    f32x4 acc[4][2];
#pragma unroll
    for (int mf = 0; mf < 4; mf++)
#pragma unroll
        for (int nf = 0; nf < 2; nf++) acc[mf][nf] = (f32x4){0.f, 0.f, 0.f, 0.f};

    const int ar = tid >> 1, acb = (tid & 1) * 32;
    const int br = tid >> 2, bcb = (tid & 3) * 16;

    v8bf pa[4], pb[2];
    {
        const bf16* ap = &A[(size_t)(bm + ar) * K + acb];
        const bf16* bp = &W[(size_t)(bn + br) * K + bcb];
#pragma unroll
        for (int u = 0; u < 4; u++) pa[u] = *(const v8bf*)&ap[8 * u];
#pragma unroll
        for (int u = 0; u < 2; u++) pb[u] = *(const v8bf*)&bp[8 * u];
#pragma unroll
        for (int u = 0; u < 4; u++) *(v8bf*)&As[ar][acb + 8 * u] = pa[u];
#pragma unroll
        for (int u = 0; u < 2; u++) *(v8bf*)&Bs[br][bcb + 8 * u] = pb[u];
    }

    for (int kt = 0; kt < K; kt += 64) {
        __syncthreads();
        const bool more = (kt + 64) < K;
        if (more) {
            const bf16* ap = &A[(size_t)(bm + ar) * K + kt + 64 + acb];
            const bf16* bp = &W[(size_t)(bn + br) * K + kt + 64 + bcb];
#pragma unroll
            for (int u = 0; u < 4; u++) pa[u] = *(const v8bf*)&ap[8 * u];
#pragma unroll
            for (int u = 0; u < 2; u++) pb[u] = *(const v8bf*)&bp[8 * u];
        }
#pragma unroll
        for (int kf = 0; kf < 2; kf++) {
            v8bf a[4], b[2];
#pragma unroll
            for (int mf = 0; mf < 4; mf++) a[mf] = *(v8bf*)&As[wm + mf * 16 + l16][kf * 32 + quad * 8];
#pragma unroll
            for (int nf = 0; nf < 2; nf++) b[nf] = *(v8bf*)&Bs[wn + nf * 16 + l16][kf * 32 + quad * 8];
#pragma unroll
            for (int mf = 0; mf < 4; mf++)
#pragma unroll
                for (int nf = 0; nf < 2; nf++)
                    acc[mf][nf] = __builtin_amdgcn_mfma_f32_16x16x32_bf16(a[mf], b[nf], acc[mf][nf], 0, 0, 0);
        }
        __syncthreads();
        if (more) {
#pragma unroll
            for (int u = 0; u < 4; u++) *(v8bf*)&As[ar][acb + 8 * u] = pa[u];
#pragma unroll
            for (int u = 0; u < 2; u++) *(v8bf*)&Bs[br][bcb + 8 * u] = pb[u];
        }
    }
#pragma unroll
    for (int mf = 0; mf < 4; mf++)
#pragma unroll
        for (int nf = 0; nf < 2; nf++)
#pragma unroll
            for (int r = 0; r < 4; r++) {
                int row = bm + wm + mf * 16 + quad * 4 + r;
                int col = bn + wn + nf * 16 + l16;
                C[(size_t)row * N + col] = acc[mf][nf][r];
            }
}

// ---------------------------------------------------------------------------
// Flash v6b: 4-way split-K, exact leveling, P aliased onto K (LDS ~34 KB),
// exp2-domain softmax. launch_bounds(256,3): <=170 regs/wave -- NO SPILLS
// (round 10's (256,4) capped at 64 VGPR -> 720 MB scratch spill traffic).
// ---------------------------------------------------------------------------
__global__ __launch_bounds__(256, 3) void flash6(const bf16* __restrict__ Q,
                                                 const bf16* __restrict__ Kb,
                                                 const bf16* __restrict__ Vtg,
                                                 bf16* __restrict__ O0,
                                                 bf16* __restrict__ O1,
                                                 bf16* __restrict__ O2,
                                                 bf16* __restrict__ O3,
                                                 float* __restrict__ ML) {
    __shared__ bf16 KsPs[128][68];   // K tile; rows reused as P tile
    __shared__ bf16 Vt[64][132];
    const int h = blockIdx.y, kvh = h >> 2;
    const int bx = blockIdx.x;
    const int tid = threadIdx.x;
    const int w = tid >> 6, lane = tid & 63;
    const int quad = lane >> 4, l16 = lane & 15;
    const int krow = tid >> 1, kcb = (tid & 1) * 32;
    const int vr = tid >> 2, vcb = (tid & 3) * 32;
    bf16* const Ops[4] = {O0, O1, O2, O3};

    const int q0 = bx >> 1, i0 = bx & 1;

    for (int p = 0; p < 2; p++) {
        const int qb = p ? (31 - q0) : q0;
        const int j  = p ? (3 - i0) : i0;
        const int T = qb + 1;
        const int k0 = (j * T) >> 2;
        const int k1 = ((j + 1) * T) >> 2;
        bf16* Op = Ops[j];
        float* mlp = ML + (size_t)(j * NHEADS + h) * L_SEQ * 2;

        if (k0 >= k1) {   // empty piece: zero partial (block-uniform)
            for (int idx = tid; idx < 128 * 64; idx += 256) {
                int rr = idx >> 6, cc = idx & 63;
                Op[(size_t)(qb * 128 + rr) * DMODEL + h * DH + cc] = (bf16)0.f;
            }
            if (tid < 128) {
                mlp[(qb * 128 + tid) * 2 + 0] = NEG_BIG;
                mlp[(qb * 128 + tid) * 2 + 1] = 0.f;
            }
            continue;
        }

        v8bf qf[2][2];
#pragma unroll
        for (int mf = 0; mf < 2; mf++)
#pragma unroll
            for (int kf = 0; kf < 2; kf++)
                qf[mf][kf] = *(const v8bf*)&Q[(size_t)(qb * 128 + w * 32 + mf * 16 + l16) * DMODEL
                                              + h * DH + kf * 32 + quad * 8];

        f32x4 oacc[2][4];
#pragma unroll
        for (int mf = 0; mf < 2; mf++)
#pragma unroll
            for (int d = 0; d < 4; d++) oacc[mf][d] = (f32x4){0.f, 0.f, 0.f, 0.f};
        float m_i[2][4], l_i[2][4];
#pragma unroll
        for (int mf = 0; mf < 2; mf++)
#pragma unroll
            for (int r = 0; r < 4; r++) { m_i[mf][r] = NEG_BIG; l_i[mf][r] = 0.f; }

        v8bf kreg[4], vreg[4];
        {   // stage first tile of this piece
            const bf16* ks = &Kb[(size_t)(k0 * 128 + krow) * 256 + kvh * DH + kcb];
            const bf16* vs = &Vtg[(size_t)(kvh * DH + vr) * L_SEQ + k0 * 128 + vcb];
#pragma unroll
            for (int u = 0; u < 4; u++) { kreg[u] = *(const v8bf*)&ks[8 * u]; vreg[u] = *(const v8bf*)&vs[8 * u]; }
            __syncthreads();   // prior piece's LDS reads complete
#pragma unroll
            for (int u = 0; u < 4; u++) { *(v8bf*)&KsPs[krow][kcb + 8 * u] = kreg[u]; *(v8bf*)&Vt[vr][vcb + 8 * u] = vreg[u]; }
        }

        for (int kb = k0; kb < k1; kb++) {
            __syncthreads();   // staged tile visible
            if (kb + 1 < k1) {
                const bf16* ks = &Kb[(size_t)((kb + 1) * 128 + krow) * 256 + kvh * DH + kcb];
                const bf16* vs = &Vtg[(size_t)(kvh * DH + vr) * L_SEQ + (kb + 1) * 128 + vcb];
#pragma unroll
                for (int u = 0; u < 4; u++) { kreg[u] = *(const v8bf*)&ks[8 * u]; vreg[u] = *(const v8bf*)&vs[8 * u]; }
            }

            // ---- S = Q K^T (exp2-domain; scale pre-folded into Q)
            f32x4 s[2][8];
#pragma unroll
            for (int n = 0; n < 8; n++) {
                v8bf b0 = *(v8bf*)&KsPs[n * 16 + l16][quad * 8];
                v8bf b1 = *(v8bf*)&KsPs[n * 16 + l16][32 + quad * 8];
#pragma unroll
                for (int mf = 0; mf < 2; mf++) {
                    s[mf][n] = (f32x4){0.f, 0.f, 0.f, 0.f};
                    s[mf][n] = __builtin_amdgcn_mfma_f32_16x16x32_bf16(qf[mf][0], b0, s[mf][n], 0, 0, 0);
                    s[mf][n] = __builtin_amdgcn_mfma_f32_16x16x32_bf16(qf[mf][1], b1, s[mf][n], 0, 0, 0);
                }
            }

            if (kb == qb) {   // causal mask (diagonal tile only)
#pragma unroll
                for (int mf = 0; mf < 2; mf++) {
                    int rbase = qb * 128 + w * 32 + mf * 16 + quad * 4;
#pragma unroll
                    for (int n = 0; n < 8; n++) {
                        int colg = kb * 128 + n * 16 + l16;
#pragma unroll
                        for (int r = 0; r < 4; r++)
                            s[mf][n][r] = (colg <= rbase + r) ? s[mf][n][r] : NEG_BIG;
                    }
                }
            }

            // ---- online softmax (exp2 domain)
            float mx[2][4];
#pragma unroll
            for (int mf = 0; mf < 2; mf++)
#pragma unroll
                for (int r = 0; r < 4; r++) {
                    float m0 = s[mf][0][r];
#pragma unroll
                    for (int n = 1; n < 8; n++) m0 = fmaxf(m0, s[mf][n][r]);
                    mx[mf][r] = m0;
                }
#pragma unroll
            for (int off = 1; off < 16; off <<= 1)
#pragma unroll
                for (int mf = 0; mf < 2; mf++)
#pragma unroll
                    for (int r = 0; r < 4; r++)
                        mx[mf][r] = fmaxf(mx[mf][r], __shfl_xor(mx[mf][r], off));

            float alpha[2][4], mnew[2][4], rs[2][4];
#pragma unroll
            for (int mf = 0; mf < 2; mf++)
#pragma unroll
                for (int r = 0; r < 4; r++) {
                    mnew[mf][r]  = fmaxf(m_i[mf][r], mx[mf][r]);
                    alpha[mf][r] = fast_exp2(m_i[mf][r] - mnew[mf][r]);
                    rs[mf][r] = 0.f;
                }
#pragma unroll
            for (int mf = 0; mf < 2; mf++)
#pragma unroll
                for (int n = 0; n < 8; n++)
#pragma unroll
                    for (int r = 0; r < 4; r++) {
                        float pv = fast_exp2(s[mf][n][r] - mnew[mf][r]);
                        s[mf][n][r] = pv;
                        rs[mf][r] += pv;
                    }
#pragma unroll
            for (int off = 1; off < 16; off <<= 1)
#pragma unroll
                for (int mf = 0; mf < 2; mf++)
#pragma unroll
                    for (int r = 0; r < 4; r++) rs[mf][r] += __shfl_xor(rs[mf][r], off);
#pragma unroll
            for (int mf = 0; mf < 2; mf++)
#pragma unroll
                for (int r = 0; r < 4; r++) {
                    l_i[mf][r] = l_i[mf][r] * alpha[mf][r] + rs[mf][r];
                    m_i[mf][r] = mnew[mf][r];
                }
#pragma unroll
            for (int mf = 0; mf < 2; mf++)
#pragma unroll
                for (int d = 0; d < 4; d++)
#pragma unroll
                    for (int r = 0; r < 4; r++) oacc[mf][d][r] *= alpha[mf][r];

            __syncthreads();   // all K reads drained -> safe to overwrite with P

            // ---- PV in two 64-key halves; P rows [w*32,+32) wave-private
#pragma unroll
            for (int half = 0; half < 2; half++) {
#pragma unroll
                for (int mf = 0; mf < 2; mf++)
#pragma unroll
                    for (int n = 0; n < 4; n++)
#pragma unroll
                        for (int r = 0; r < 4; r++)
                            KsPs[w * 32 + mf * 16 + quad * 4 + r][n * 16 + l16] =
                                (bf16)s[mf][half * 4 + n][r];
#pragma unroll
                for (int kf = 0; kf < 2; kf++) {
#pragma unroll
                    for (int mf = 0; mf < 2; mf++) {
                        v8bf pa = *(v8bf*)&KsPs[w * 32 + mf * 16 + l16][kf * 32 + quad * 8];
#pragma unroll
                        for (int d = 0; d < 4; d++) {
                            v8bf vb = *(v8bf*)&Vt[d * 16 + l16][half * 64 + kf * 32 + quad * 8];
                            oacc[mf][d] = __builtin_amdgcn_mfma_f32_16x16x32_bf16(pa, vb, oacc[mf][d], 0, 0, 0);
                        }
                    }
                }
            }

            __syncthreads();   // P/V reads done -> safe to restage next tile
            if (kb + 1 < k1) {
#pragma unroll
                for (int u = 0; u < 4; u++) { *(v8bf*)&KsPs[krow][kcb + 8 * u] = kreg[u]; *(v8bf*)&Vt[vr][vcb + 8 * u] = vreg[u]; }
            }
        }

        // ---- unnormalized partial write
#pragma unroll
        for (int mf = 0; mf < 2; mf++)
#pragma unroll
            for (int d = 0; d < 4; d++)
#pragma unroll
                for (int r = 0; r < 4; r++) {
                    int row = qb * 128 + w * 32 + mf * 16 + quad * 4 + r;
                    Op[(size_t)row * DMODEL + h * DH + d * 16 + l16] = (bf16)oacc[mf][d][r];
                }
        if (l16 == 0) {
#pragma unroll
            for (int mf = 0; mf < 2; mf++)
#pragma unroll
                for (int r = 0; r < 4; r++) {
                    int row = qb * 128 + w * 32 + mf * 16 + quad * 4 + r;
                    mlp[row * 2 + 0] = m_i[mf][r];
                    mlp[row * 2 + 1] = l_i[mf][r];
                }
        }
    }
}

// ---------------------------------------------------------------------------
// Combine 4 split-K partials into normalized Attn (bf16). exp2 domain.
// ---------------------------------------------------------------------------
__global__ void combine4(const bf16* __restrict__ O0, const bf16* __restrict__ O1,
                         const bf16* __restrict__ O2, const bf16* __restrict__ O3,
                         const float* __restrict__ ML, bf16* __restrict__ Attn) {
    int gid = blockIdx.x * 256 + threadIdx.x;
    int row = gid >> 8;
    int cg = (gid & 255) * 4;
    int h = cg >> 6;
    float m[4], l[4];
#pragma unroll
    for (int j = 0; j < 4; j++) {
        const float* ml = ML + (((size_t)(j * NHEADS + h) * L_SEQ) + row) * 2;
        m[j] = ml[0]; l[j] = ml[1];
    }
    float mmax = fmaxf(fmaxf(m[0], m[1]), fmaxf(m[2], m[3]));
    float a[4], denom = 0.f;
#pragma unroll
    for (int j = 0; j < 4; j++) { a[j] = fast_exp2(m[j] - mmax); denom += a[j] * l[j]; }
    float inv = 1.f / denom;
    v4bf o0 = *(const v4bf*)&O0[(size_t)row * DMODEL + cg];
    v4bf o1 = *(const v4bf*)&O1[(size_t)row * DMODEL + cg];
    v4bf o2 = *(const v4bf*)&O2[(size_t)row * DMODEL + cg];
    v4bf o3 = *(const v4bf*)&O3[(size_t)row * DMODEL + cg];
    v4bf res;
#pragma unroll
    for (int jj = 0; jj < 4; jj++)
        res[jj] = (bf16)((a[0] * (float)o0[jj] + a[1] * (float)o1[jj] +
                          a[2] * (float)o2[jj] + a[3] * (float)o3[jj]) * inv);
    *(v4bf*)&Attn[(size_t)row * DMODEL + cg] = res;
}

// ---------------------------------------------------------------------------
extern "C" void kernel_launch(void* const* d_in, const int* in_sizes, int n_in,
                              void* d_out, int out_size, void* d_ws, size_t ws_size,
                              hipStream_t stream) {
    const float* x  = (const float*)d_in[0];
    const float* Wq = (const float*)d_in[1];
    const float* Wk = (const float*)d_in[2];
    const float* Wv = (const float*)d_in[3];
    const float* Wo = (const float*)d_in[4];
    const int*   tp = (const int*)d_in[5];
    float* out = (float*)d_out;

    bf16*  xb    = (bf16*)d_ws;               // 4,194,304 (reused as Attn)
    bf16*  wqkvb = xb    + 4194304;           // 1,572,864
    bf16*  wob   = wqkvb + 1572864;           // 1,048,576
    bf16*  Qb    = wob   + 1048576;           // 4,194,304
    bf16*  Kb    = Qb    + 4194304;           // 1,048,576  [4096][256]
    bf16*  Vtg   = Kb    + 1048576;           // 1,048,576  [256][4096]
    bf16*  O2    = Vtg   + 1048576;           // 4,194,304 partial j=2
    bf16*  O3    = O2    + 4194304;           // 4,194,304 partial j=3
    float* MLf   = (float*)(O3 + 4194304);    // 524,288 f32
    bf16*  Attn  = xb;
    bf16*  O0    = (bf16*)d_out;              // partial j=0 (in f32 out buffer)
    bf16*  O1    = O0 + 4194304;              // partial j=1

    convert_all<<<6656, 256, 0, stream>>>(x, Wq, Wk, Wv, Wo, xb, wqkvb, wob);
    gemm_qkv<<<dim3(24, 32), 256, 0, stream>>>(xb, wqkvb, Qb, Kb, Vtg, tp);
    flash6<<<dim3(64, NHEADS), 256, 0, stream>>>(Qb, Kb, Vtg, O0, O1, O2, O3, MLf);
    combine4<<<4096, 256, 0, stream>>>(O0, O1, O2, O3, MLf, Attn);
    gemm_out<<<dim3(16, 32), 256, 0, stream>>>(Attn, wob, out);
}

// Round 12
// 263.172 us; speedup vs baseline: 1.5097x; 1.1689x over previous
//
#include <hip/hip_runtime.h>
#include <hip/hip_bf16.h>
#include <math.h>

typedef __bf16 bf16;
typedef __bf16 v8bf __attribute__((ext_vector_type(8)));
typedef __bf16 v4bf __attribute__((ext_vector_type(4)));
typedef float f32x4 __attribute__((ext_vector_type(4)));

#define L_SEQ 4096
#define DMODEL 1024
#define NHEADS 16
#define DH 64
#define NEG_BIG (-1e30f)
#define LN1E4_64 0.14391156f     // ln(10000)/64
#define QSCALE 0.18033688f       // (1/sqrt(64)) * log2(e)  -> exp2-domain scores

__device__ inline float fast_exp2(float x) { return __builtin_amdgcn_exp2f(x); }

// ---------------------------------------------------------------------------
// One-shot f32 -> bf16 conversion. xb[4096*1024], wqkvb[1536*1024], wob[1024*1024].
// ---------------------------------------------------------------------------
__global__ void convert_all(const float* __restrict__ x, const float* __restrict__ wq,
                            const float* __restrict__ wk, const float* __restrict__ wv,
                            const float* __restrict__ wo,
                            bf16* __restrict__ xb, bf16* __restrict__ wqkvb,
                            bf16* __restrict__ wob) {
    int i = (blockIdx.x * 256 + threadIdx.x) * 4;
    const float* src;
    bf16* dst;
    if (i < 4194304)      { src = x  + i;             dst = xb    + i; }
    else if (i < 5242880) { src = wq + (i - 4194304); dst = wqkvb + (i - 4194304); }
    else if (i < 5505024) { src = wk + (i - 5242880); dst = wqkvb + 1048576 + (i - 5242880); }
    else if (i < 5767168) { src = wv + (i - 5505024); dst = wqkvb + 1310720 + (i - 5505024); }
    else                  { src = wo + (i - 5767168); dst = wob   + (i - 5767168); }
    f32x4 v = *(const f32x4*)src;
    v4bf r;
#pragma unroll
    for (int j = 0; j < 4; j++) r[j] = (bf16)v[j];
    *(v4bf*)dst = r;
}

// ---------------------------------------------------------------------------
// Fused QKV projection: 128x64 tiles, 256 threads (4 waves), reg prefetch.
// Grid (24, 32) = 768 blocks. Q pre-scaled by QSCALE.
// ---------------------------------------------------------------------------
__global__ __launch_bounds__(256) void gemm_qkv(const bf16* __restrict__ A,
                                                const bf16* __restrict__ W,
                                                bf16* __restrict__ Qb,
                                                bf16* __restrict__ Kb,
                                                bf16* __restrict__ Vtg,
                                                const int* __restrict__ tp) {
    __shared__ bf16 As[128][68];
    __shared__ bf16 Bs[64][68];
    const int K = 1024;
    const int tid = threadIdx.x;
    const int w = tid >> 6, lane = tid & 63;
    const int quad = lane >> 4, l16 = lane & 15;
    const int wm = (w & 1) * 64, wn = (w >> 1) * 32;
    const int bm = blockIdx.y * 128, bn = blockIdx.x * 64;

    f32x4 acc[4][2];
#pragma unroll
    for (int mf = 0; mf < 4; mf++)
#pragma unroll
        for (int nf = 0; nf < 2; nf++) acc[mf][nf] = (f32x4){0.f, 0.f, 0.f, 0.f};

    const int ar = tid >> 1, acb = (tid & 1) * 32;   // A: 128 rows x 64 cols
    const int br = tid >> 2, bcb = (tid & 3) * 16;   // B: 64 rows x 64 cols

    v8bf pa[4], pb[2];
    {
        const bf16* ap = &A[(size_t)(bm + ar) * K + acb];
        const bf16* bp = &W[(size_t)(bn + br) * K + bcb];
#pragma unroll
        for (int u = 0; u < 4; u++) pa[u] = *(const v8bf*)&ap[8 * u];
#pragma unroll
        for (int u = 0; u < 2; u++) pb[u] = *(const v8bf*)&bp[8 * u];
#pragma unroll
        for (int u = 0; u < 4; u++) *(v8bf*)&As[ar][acb + 8 * u] = pa[u];
#pragma unroll
        for (int u = 0; u < 2; u++) *(v8bf*)&Bs[br][bcb + 8 * u] = pb[u];
    }

    for (int kt = 0; kt < K; kt += 64) {
        __syncthreads();
        const bool more = (kt + 64) < K;
        if (more) {
            const bf16* ap = &A[(size_t)(bm + ar) * K + kt + 64 + acb];
            const bf16* bp = &W[(size_t)(bn + br) * K + kt + 64 + bcb];
#pragma unroll
            for (int u = 0; u < 4; u++) pa[u] = *(const v8bf*)&ap[8 * u];
#pragma unroll
            for (int u = 0; u < 2; u++) pb[u] = *(const v8bf*)&bp[8 * u];
        }
#pragma unroll
        for (int kf = 0; kf < 2; kf++) {
            v8bf a[4], b[2];
#pragma unroll
            for (int mf = 0; mf < 4; mf++) a[mf] = *(v8bf*)&As[wm + mf * 16 + l16][kf * 32 + quad * 8];
#pragma unroll
            for (int nf = 0; nf < 2; nf++) b[nf] = *(v8bf*)&Bs[wn + nf * 16 + l16][kf * 32 + quad * 8];
#pragma unroll
            for (int mf = 0; mf < 4; mf++)
#pragma unroll
                for (int nf = 0; nf < 2; nf++)
                    acc[mf][nf] = __builtin_amdgcn_mfma_f32_16x16x32_bf16(a[mf], b[nf], acc[mf][nf], 0, 0, 0);
        }
        __syncthreads();
        if (more) {
#pragma unroll
            for (int u = 0; u < 4; u++) *(v8bf*)&As[ar][acb + 8 * u] = pa[u];
#pragma unroll
            for (int u = 0; u < 2; u++) *(v8bf*)&Bs[br][bcb + 8 * u] = pb[u];
        }
    }

    if (bn < 1024) {          // ---- Q region: RoPE + QSCALE ----
#pragma unroll
        for (int mf = 0; mf < 4; mf++) {
            int pos_[4];
#pragma unroll
            for (int r = 0; r < 4; r++) pos_[r] = tp[bm + wm + mf * 16 + quad * 4 + r];
#pragma unroll
            for (int nf = 0; nf < 2; nf++) {
                const int col = bn + wn + nf * 16 + l16;
                float fr = __expf(-(float)((col & 63) & ~1) * LN1E4_64);
#pragma unroll
                for (int r = 0; r < 4; r++) {
                    float v = acc[mf][nf][r];
                    float sn, cs;
                    __sincosf((float)pos_[r] * fr, &sn, &cs);
                    float p = __shfl_xor(v, 1);
                    float res = (l16 & 1) ? (p * sn + v * cs) : (v * cs - p * sn);
                    int row = bm + wm + mf * 16 + quad * 4 + r;
                    Qb[(size_t)row * DMODEL + col] = (bf16)(res * QSCALE);
                }
            }
        }
    } else if (bn < 1280) {   // ---- K region: RoPE ----
#pragma unroll
        for (int mf = 0; mf < 4; mf++) {
            int pos_[4];
#pragma unroll
            for (int r = 0; r < 4; r++) pos_[r] = tp[bm + wm + mf * 16 + quad * 4 + r];
#pragma unroll
            for (int nf = 0; nf < 2; nf++) {
                const int kcol = bn - 1024 + wn + nf * 16 + l16;
                float fr = __expf(-(float)((kcol & 63) & ~1) * LN1E4_64);
#pragma unroll
                for (int r = 0; r < 4; r++) {
                    float v = acc[mf][nf][r];
                    float sn, cs;
                    __sincosf((float)pos_[r] * fr, &sn, &cs);
                    float p = __shfl_xor(v, 1);
                    float res = (l16 & 1) ? (p * sn + v * cs) : (v * cs - p * sn);
                    int row = bm + wm + mf * 16 + quad * 4 + r;
                    Kb[(size_t)row * 256 + kcol] = (bf16)res;
                }
            }
        }
    } else {                  // ---- V region: transposed store ----
#pragma unroll
        for (int mf = 0; mf < 4; mf++)
#pragma unroll
            for (int nf = 0; nf < 2; nf++) {
                v4bf pk;
#pragma unroll
                for (int r = 0; r < 4; r++) pk[r] = (bf16)acc[mf][nf][r];
                int vcol = bn - 1280 + wn + nf * 16 + l16;
                int row = bm + wm + mf * 16 + quad * 4;
                *(v4bf*)&Vtg[(size_t)vcol * L_SEQ + row] = pk;
            }
    }
}

// ---------------------------------------------------------------------------
// Output projection: 128x64 tiles, 256 threads. Grid (16, 32) = 512 blocks.
// ---------------------------------------------------------------------------
__global__ __launch_bounds__(256) void gemm_out(const bf16* __restrict__ A,
                                                const bf16* __restrict__ W,
                                                float* __restrict__ C) {
    __shared__ bf16 As[128][68];
    __shared__ bf16 Bs[64][68];
    const int K = 1024, N = 1024;
    const int tid = threadIdx.x;
    const int w = tid >> 6, lane = tid & 63;
    const int quad = lane >> 4, l16 = lane & 15;
    const int wm = (w & 1) * 64, wn = (w >> 1) * 32;
    const int bm = blockIdx.y * 128, bn = blockIdx.x * 64;

    f32x4 acc[4][2];
#pragma unroll
    for (int mf = 0; mf < 4; mf++)
#pragma unroll
        for (int nf = 0; nf < 2; nf++) acc[mf][nf] = (f32x4){0.f, 0.f, 0.f, 0.f};

    const int ar = tid >> 1, acb = (tid & 1) * 32;
    const int br = tid >> 2, bcb = (tid & 3) * 16;

    v8bf pa[4], pb[2];
    {
        const bf16* ap = &A[(size_t)(bm + ar) * K + acb];
        const bf16* bp = &W[(size_t)(bn + br) * K + bcb];
#pragma unroll
        for (int u = 0; u < 4; u++) pa[u] = *(const v8bf*)&ap[8 * u];
#pragma unroll
        for (int u = 0; u < 2; u++) pb[u] = *(const v8bf*)&bp[8 * u];
#pragma unroll
        for (int u = 0; u < 4; u++) *(v8bf*)&As[ar][acb + 8 * u] = pa[u];
#pragma unroll
        for (int u = 0; u < 2; u++) *(v8bf*)&Bs[br][bcb + 8 * u] = pb[u];
    }

    for (int kt = 0; kt < K; kt += 64) {
        __syncthreads();
        const bool more = (kt + 64) < K;
        if (more) {
            const bf16* ap = &A[(size_t)(bm + ar) * K + kt + 64 + acb];
            const bf16* bp = &W[(size_t)(bn + br) * K + kt + 64 + bcb];
#pragma unroll
            for (int u = 0; u < 4; u++) pa[u] = *(const v8bf*)&ap[8 * u];
#pragma unroll
            for (int u = 0; u < 2; u++) pb[u] = *(const v8bf*)&bp[8 * u];
        }
#pragma unroll
        for (int kf = 0; kf < 2; kf++) {
            v8bf a[4], b[2];
#pragma unroll
            for (int mf = 0; mf < 4; mf++) a[mf] = *(v8bf*)&As[wm + mf * 16 + l16][kf * 32 + quad * 8];
#pragma unroll
            for (int nf = 0; nf < 2; nf++) b[nf] = *(v8bf*)&Bs[wn + nf * 16 + l16][kf * 32 + quad * 8];
#pragma unroll
            for (int mf = 0; mf < 4; mf++)
#pragma unroll
                for (int nf = 0; nf < 2; nf++)
                    acc[mf][nf] = __builtin_amdgcn_mfma_f32_16x16x32_bf16(a[mf], b[nf], acc[mf][nf], 0, 0, 0);
        }
        __syncthreads();
        if (more) {
#pragma unroll
            for (int u = 0; u < 4; u++) *(v8bf*)&As[ar][acb + 8 * u] = pa[u];
#pragma unroll
            for (int u = 0; u < 2; u++) *(v8bf*)&Bs[br][bcb + 8 * u] = pb[u];
        }
    }
#pragma unroll
    for (int mf = 0; mf < 4; mf++)
#pragma unroll
        for (int nf = 0; nf < 2; nf++)
#pragma unroll
            for (int r = 0; r < 4; r++) {
                int row = bm + wm + mf * 16 + quad * 4 + r;
                int col = bn + wn + nf * 16 + l16;
                C[(size_t)row * N + col] = acc[mf][nf][r];
            }
}

// ---------------------------------------------------------------------------
// Flash v7: 4-way split-K + P-on-K alias (34 KB LDS), exp2 softmax.
// NO register prefetch (round 11's live set spilled at (256,3): 299 MB scratch
// writes). Staging is direct global->LDS between barriers; latency hidden by
// 3 blocks/CU (m97-style implicit overlap). launch_bounds(256,3).
// ---------------------------------------------------------------------------
__global__ __launch_bounds__(256, 3) void flash7(const bf16* __restrict__ Q,
                                                 const bf16* __restrict__ Kb,
                                                 const bf16* __restrict__ Vtg,
                                                 bf16* __restrict__ O0,
                                                 bf16* __restrict__ O1,
                                                 bf16* __restrict__ O2,
                                                 bf16* __restrict__ O3,
                                                 float* __restrict__ ML) {
    __shared__ bf16 KsPs[128][68];   // K tile; rows reused as P tile
    __shared__ bf16 Vt[64][132];
    const int h = blockIdx.y, kvh = h >> 2;
    const int bx = blockIdx.x;
    const int tid = threadIdx.x;
    const int w = tid >> 6, lane = tid & 63;
    const int quad = lane >> 4, l16 = lane & 15;
    const int krow = tid >> 1, kcb = (tid & 1) * 32;
    const int vr = tid >> 2, vcb = (tid & 3) * 32;
    bf16* const Ops[4] = {O0, O1, O2, O3};

    const int q0 = bx >> 1, i0 = bx & 1;

    for (int p = 0; p < 2; p++) {
        const int qb = p ? (31 - q0) : q0;
        const int j  = p ? (3 - i0) : i0;
        const int T = qb + 1;
        const int k0 = (j * T) >> 2;
        const int k1 = ((j + 1) * T) >> 2;
        bf16* Op = Ops[j];
        float* mlp = ML + (size_t)(j * NHEADS + h) * L_SEQ * 2;

        if (k0 >= k1) {   // empty piece: zero partial (block-uniform)
            for (int idx = tid; idx < 128 * 64; idx += 256) {
                int rr = idx >> 6, cc = idx & 63;
                Op[(size_t)(qb * 128 + rr) * DMODEL + h * DH + cc] = (bf16)0.f;
            }
            if (tid < 128) {
                mlp[(qb * 128 + tid) * 2 + 0] = NEG_BIG;
                mlp[(qb * 128 + tid) * 2 + 1] = 0.f;
            }
            continue;
        }

        v8bf qf[2][2];
#pragma unroll
        for (int mf = 0; mf < 2; mf++)
#pragma unroll
            for (int kf = 0; kf < 2; kf++)
                qf[mf][kf] = *(const v8bf*)&Q[(size_t)(qb * 128 + w * 32 + mf * 16 + l16) * DMODEL
                                              + h * DH + kf * 32 + quad * 8];

        f32x4 oacc[2][4];
#pragma unroll
        for (int mf = 0; mf < 2; mf++)
#pragma unroll
            for (int d = 0; d < 4; d++) oacc[mf][d] = (f32x4){0.f, 0.f, 0.f, 0.f};
        float m_i[2][4], l_i[2][4];
#pragma unroll
        for (int mf = 0; mf < 2; mf++)
#pragma unroll
            for (int r = 0; r < 4; r++) { m_i[mf][r] = NEG_BIG; l_i[mf][r] = 0.f; }

        for (int kb = k0; kb < k1; kb++) {
            __syncthreads();   // prior step's LDS reads (P/V) complete
            {   // stage K and V^T directly global -> LDS (coalesced)
                const bf16* ks = &Kb[(size_t)(kb * 128 + krow) * 256 + kvh * DH + kcb];
                const bf16* vs = &Vtg[(size_t)(kvh * DH + vr) * L_SEQ + kb * 128 + vcb];
#pragma unroll
                for (int u = 0; u < 4; u++) {
                    *(v8bf*)&KsPs[krow][kcb + 8 * u] = *(const v8bf*)&ks[8 * u];
                    *(v8bf*)&Vt[vr][vcb + 8 * u]    = *(const v8bf*)&vs[8 * u];
                }
            }
            __syncthreads();   // staged tile visible

            // ---- S = Q K^T (exp2-domain; scale pre-folded into Q)
            f32x4 s[2][8];
#pragma unroll
            for (int n = 0; n < 8; n++) {
                v8bf b0 = *(v8bf*)&KsPs[n * 16 + l16][quad * 8];
                v8bf b1 = *(v8bf*)&KsPs[n * 16 + l16][32 + quad * 8];
#pragma unroll
                for (int mf = 0; mf < 2; mf++) {
                    s[mf][n] = (f32x4){0.f, 0.f, 0.f, 0.f};
                    s[mf][n] = __builtin_amdgcn_mfma_f32_16x16x32_bf16(qf[mf][0], b0, s[mf][n], 0, 0, 0);
                    s[mf][n] = __builtin_amdgcn_mfma_f32_16x16x32_bf16(qf[mf][1], b1, s[mf][n], 0, 0, 0);
                }
            }

            if (kb == qb) {   // causal mask (diagonal tile only)
#pragma unroll
                for (int mf = 0; mf < 2; mf++) {
                    int rbase = qb * 128 + w * 32 + mf * 16 + quad * 4;
#pragma unroll
                    for (int n = 0; n < 8; n++) {
                        int colg = kb * 128 + n * 16 + l16;
#pragma unroll
                        for (int r = 0; r < 4; r++)
                            s[mf][n][r] = (colg <= rbase + r) ? s[mf][n][r] : NEG_BIG;
                    }
                }
            }

            // ---- online softmax (exp2 domain)
            float mx[2][4];
#pragma unroll
            for (int mf = 0; mf < 2; mf++)
#pragma unroll
                for (int r = 0; r < 4; r++) {
                    float m0 = s[mf][0][r];
#pragma unroll
                    for (int n = 1; n < 8; n++) m0 = fmaxf(m0, s[mf][n][r]);
                    mx[mf][r] = m0;
                }
#pragma unroll
            for (int off = 1; off < 16; off <<= 1)
#pragma unroll
                for (int mf = 0; mf < 2; mf++)
#pragma unroll
                    for (int r = 0; r < 4; r++)
                        mx[mf][r] = fmaxf(mx[mf][r], __shfl_xor(mx[mf][r], off));

            float alpha[2][4], mnew[2][4], rs[2][4];
#pragma unroll
            for (int mf = 0; mf < 2; mf++)
#pragma unroll
                for (int r = 0; r < 4; r++) {
                    mnew[mf][r]  = fmaxf(m_i[mf][r], mx[mf][r]);
                    alpha[mf][r] = fast_exp2(m_i[mf][r] - mnew[mf][r]);
                    rs[mf][r] = 0.f;
                }
#pragma unroll
            for (int mf = 0; mf < 2; mf++)
#pragma unroll
                for (int n = 0; n < 8; n++)
#pragma unroll
                    for (int r = 0; r < 4; r++) {
                        float pv = fast_exp2(s[mf][n][r] - mnew[mf][r]);
                        s[mf][n][r] = pv;
                        rs[mf][r] += pv;
                    }
#pragma unroll
            for (int off = 1; off < 16; off <<= 1)
#pragma unroll
                for (int mf = 0; mf < 2; mf++)
#pragma unroll
                    for (int r = 0; r < 4; r++) rs[mf][r] += __shfl_xor(rs[mf][r], off);
#pragma unroll
            for (int mf = 0; mf < 2; mf++)
#pragma unroll
                for (int r = 0; r < 4; r++) {
                    l_i[mf][r] = l_i[mf][r] * alpha[mf][r] + rs[mf][r];
                    m_i[mf][r] = mnew[mf][r];
                }
#pragma unroll
            for (int mf = 0; mf < 2; mf++)
#pragma unroll
                for (int d = 0; d < 4; d++)
#pragma unroll
                    for (int r = 0; r < 4; r++) oacc[mf][d][r] *= alpha[mf][r];

            __syncthreads();   // all K reads drained -> safe to overwrite with P

            // ---- PV in two 64-key halves; P rows [w*32,+32) wave-private
#pragma unroll
            for (int half = 0; half < 2; half++) {
#pragma unroll
                for (int mf = 0; mf < 2; mf++)
#pragma unroll
                    for (int n = 0; n < 4; n++)
#pragma unroll
                        for (int r = 0; r < 4; r++)
                            KsPs[w * 32 + mf * 16 + quad * 4 + r][n * 16 + l16] =
                                (bf16)s[mf][half * 4 + n][r];
#pragma unroll
                for (int kf = 0; kf < 2; kf++) {
#pragma unroll
                    for (int mf = 0; mf < 2; mf++) {
                        v8bf pa = *(v8bf*)&KsPs[w * 32 + mf * 16 + l16][kf * 32 + quad * 8];
#pragma unroll
                        for (int d = 0; d < 4; d++) {
                            v8bf vb = *(v8bf*)&Vt[d * 16 + l16][half * 64 + kf * 32 + quad * 8];
                            oacc[mf][d] = __builtin_amdgcn_mfma_f32_16x16x32_bf16(pa, vb, oacc[mf][d], 0, 0, 0);
                        }
                    }
                }
            }
        }

        // ---- unnormalized partial write
#pragma unroll
        for (int mf = 0; mf < 2; mf++)
#pragma unroll
            for (int d = 0; d < 4; d++)
#pragma unroll
                for (int r = 0; r < 4; r++) {
                    int row = qb * 128 + w * 32 + mf * 16 + quad * 4 + r;
                    Op[(size_t)row * DMODEL + h * DH + d * 16 + l16] = (bf16)oacc[mf][d][r];
                }
        if (l16 == 0) {
#pragma unroll
            for (int mf = 0; mf < 2; mf++)
#pragma unroll
                for (int r = 0; r < 4; r++) {
                    int row = qb * 128 + w * 32 + mf * 16 + quad * 4 + r;
                    mlp[row * 2 + 0] = m_i[mf][r];
                    mlp[row * 2 + 1] = l_i[mf][r];
                }
        }
    }
}

// ---------------------------------------------------------------------------
// Combine 4 split-K partials into normalized Attn (bf16). exp2 domain.
// ---------------------------------------------------------------------------
__global__ void combine4(const bf16* __restrict__ O0, const bf16* __restrict__ O1,
                         const bf16* __restrict__ O2, const bf16* __restrict__ O3,
                         const float* __restrict__ ML, bf16* __restrict__ Attn) {
    int gid = blockIdx.x * 256 + threadIdx.x;
    int row = gid >> 8;
    int cg = (gid & 255) * 4;
    int h = cg >> 6;
    float m[4], l[4];
#pragma unroll
    for (int j = 0; j < 4; j++) {
        const float* ml = ML + (((size_t)(j * NHEADS + h) * L_SEQ) + row) * 2;
        m[j] = ml[0]; l[j] = ml[1];
    }
    float mmax = fmaxf(fmaxf(m[0], m[1]), fmaxf(m[2], m[3]));
    float a[4], denom = 0.f;
#pragma unroll
    for (int j = 0; j < 4; j++) { a[j] = fast_exp2(m[j] - mmax); denom += a[j] * l[j]; }
    float inv = 1.f / denom;
    v4bf o0 = *(const v4bf*)&O0[(size_t)row * DMODEL + cg];
    v4bf o1 = *(const v4bf*)&O1[(size_t)row * DMODEL + cg];
    v4bf o2 = *(const v4bf*)&O2[(size_t)row * DMODEL + cg];
    v4bf o3 = *(const v4bf*)&O3[(size_t)row * DMODEL + cg];
    v4bf res;
#pragma unroll
    for (int jj = 0; jj < 4; jj++)
        res[jj] = (bf16)((a[0] * (float)o0[jj] + a[1] * (float)o1[jj] +
                          a[2] * (float)o2[jj] + a[3] * (float)o3[jj]) * inv);
    *(v4bf*)&Attn[(size_t)row * DMODEL + cg] = res;
}

// ---------------------------------------------------------------------------
extern "C" void kernel_launch(void* const* d_in, const int* in_sizes, int n_in,
                              void* d_out, int out_size, void* d_ws, size_t ws_size,
                              hipStream_t stream) {
    const float* x  = (const float*)d_in[0];
    const float* Wq = (const float*)d_in[1];
    const float* Wk = (const float*)d_in[2];
    const float* Wv = (const float*)d_in[3];
    const float* Wo = (const float*)d_in[4];
    const int*   tp = (const int*)d_in[5];
    float* out = (float*)d_out;

    bf16*  xb    = (bf16*)d_ws;               // 4,194,304 (reused as Attn)
    bf16*  wqkvb = xb    + 4194304;           // 1,572,864
    bf16*  wob   = wqkvb + 1572864;           // 1,048,576
    bf16*  Qb    = wob   + 1048576;           // 4,194,304
    bf16*  Kb    = Qb    + 4194304;           // 1,048,576  [4096][256]
    bf16*  Vtg   = Kb    + 1048576;           // 1,048,576  [256][4096]
    bf16*  O2    = Vtg   + 1048576;           // 4,194,304 partial j=2
    bf16*  O3    = O2    + 4194304;           // 4,194,304 partial j=3
    float* MLf   = (float*)(O3 + 4194304);    // 524,288 f32
    bf16*  Attn  = xb;
    bf16*  O0    = (bf16*)d_out;              // partial j=0 (in f32 out buffer)
    bf16*  O1    = O0 + 4194304;              // partial j=1

    convert_all<<<6656, 256, 0, stream>>>(x, Wq, Wk, Wv, Wo, xb, wqkvb, wob);
    gemm_qkv<<<dim3(24, 32), 256, 0, stream>>>(xb, wqkvb, Qb, Kb, Vtg, tp);
    flash7<<<dim3(64, NHEADS), 256, 0, stream>>>(Qb, Kb, Vtg, O0, O1, O2, O3, MLf);
    combine4<<<4096, 256, 0, stream>>>(O0, O1, O2, O3, MLf, Attn);
    gemm_out<<<dim3(16, 32), 256, 0, stream>>>(Attn, wob, out);
}

// Round 13
// 237.251 us; speedup vs baseline: 1.6747x; 1.1093x over previous
//
#include <hip/hip_runtime.h>
#include <hip/hip_bf16.h>
#include <math.h>

typedef __bf16 bf16;
typedef __bf16 v8bf __attribute__((ext_vector_type(8)));
typedef __bf16 v4bf __attribute__((ext_vector_type(4)));
typedef float f32x4 __attribute__((ext_vector_type(4)));

#define L_SEQ 4096
#define DMODEL 1024
#define NHEADS 16
#define DH 64
#define NEG_BIG (-1e30f)
#define LN1E4_64 0.14391156f     // ln(10000)/64
#define QSCALE 0.18033688f       // (1/sqrt(64)) * log2(e)  -> exp2-domain scores

__device__ inline float fast_exp2(float x) { return __builtin_amdgcn_exp2f(x); }

// ---------------------------------------------------------------------------
// One-shot f32 -> bf16 conversion. xb[4096*1024], wqkvb[1536*1024], wob[1024*1024].
// ---------------------------------------------------------------------------
__global__ void convert_all(const float* __restrict__ x, const float* __restrict__ wq,
                            const float* __restrict__ wk, const float* __restrict__ wv,
                            const float* __restrict__ wo,
                            bf16* __restrict__ xb, bf16* __restrict__ wqkvb,
                            bf16* __restrict__ wob) {
    int i = (blockIdx.x * 256 + threadIdx.x) * 4;
    const float* src;
    bf16* dst;
    if (i < 4194304)      { src = x  + i;             dst = xb    + i; }
    else if (i < 5242880) { src = wq + (i - 4194304); dst = wqkvb + (i - 4194304); }
    else if (i < 5505024) { src = wk + (i - 5242880); dst = wqkvb + 1048576 + (i - 5242880); }
    else if (i < 5767168) { src = wv + (i - 5505024); dst = wqkvb + 1310720 + (i - 5505024); }
    else                  { src = wo + (i - 5767168); dst = wob   + (i - 5767168); }
    f32x4 v = *(const f32x4*)src;
    v4bf r;
#pragma unroll
    for (int j = 0; j < 4; j++) r[j] = (bf16)v[j];
    *(v4bf*)dst = r;
}

// ---------------------------------------------------------------------------
// Fused QKV projection: 128x64 tiles, 256 threads (4 waves), reg prefetch.
// Grid (24, 32) = 768 blocks. Q pre-scaled by QSCALE.
// ---------------------------------------------------------------------------
__global__ __launch_bounds__(256) void gemm_qkv(const bf16* __restrict__ A,
                                                const bf16* __restrict__ W,
                                                bf16* __restrict__ Qb,
                                                bf16* __restrict__ Kb,
                                                bf16* __restrict__ Vtg,
                                                const int* __restrict__ tp) {
    __shared__ bf16 As[128][68];
    __shared__ bf16 Bs[64][68];
    const int K = 1024;
    const int tid = threadIdx.x;
    const int w = tid >> 6, lane = tid & 63;
    const int quad = lane >> 4, l16 = lane & 15;
    const int wm = (w & 1) * 64, wn = (w >> 1) * 32;
    const int bm = blockIdx.y * 128, bn = blockIdx.x * 64;

    f32x4 acc[4][2];
#pragma unroll
    for (int mf = 0; mf < 4; mf++)
#pragma unroll
        for (int nf = 0; nf < 2; nf++) acc[mf][nf] = (f32x4){0.f, 0.f, 0.f, 0.f};

    const int ar = tid >> 1, acb = (tid & 1) * 32;
    const int br = tid >> 2, bcb = (tid & 3) * 16;

    v8bf pa[4], pb[2];
    {
        const bf16* ap = &A[(size_t)(bm + ar) * K + acb];
        const bf16* bp = &W[(size_t)(bn + br) * K + bcb];
#pragma unroll
        for (int u = 0; u < 4; u++) pa[u] = *(const v8bf*)&ap[8 * u];
#pragma unroll
        for (int u = 0; u < 2; u++) pb[u] = *(const v8bf*)&bp[8 * u];
#pragma unroll
        for (int u = 0; u < 4; u++) *(v8bf*)&As[ar][acb + 8 * u] = pa[u];
#pragma unroll
        for (int u = 0; u < 2; u++) *(v8bf*)&Bs[br][bcb + 8 * u] = pb[u];
    }

    for (int kt = 0; kt < K; kt += 64) {
        __syncthreads();
        const bool more = (kt + 64) < K;
        if (more) {
            const bf16* ap = &A[(size_t)(bm + ar) * K + kt + 64 + acb];
            const bf16* bp = &W[(size_t)(bn + br) * K + kt + 64 + bcb];
#pragma unroll
            for (int u = 0; u < 4; u++) pa[u] = *(const v8bf*)&ap[8 * u];
#pragma unroll
            for (int u = 0; u < 2; u++) pb[u] = *(const v8bf*)&bp[8 * u];
        }
#pragma unroll
        for (int kf = 0; kf < 2; kf++) {
            v8bf a[4], b[2];
#pragma unroll
            for (int mf = 0; mf < 4; mf++) a[mf] = *(v8bf*)&As[wm + mf * 16 + l16][kf * 32 + quad * 8];
#pragma unroll
            for (int nf = 0; nf < 2; nf++) b[nf] = *(v8bf*)&Bs[wn + nf * 16 + l16][kf * 32 + quad * 8];
#pragma unroll
            for (int mf = 0; mf < 4; mf++)
#pragma unroll
                for (int nf = 0; nf < 2; nf++)
                    acc[mf][nf] = __builtin_amdgcn_mfma_f32_16x16x32_bf16(a[mf], b[nf], acc[mf][nf], 0, 0, 0);
        }
        __syncthreads();
        if (more) {
#pragma unroll
            for (int u = 0; u < 4; u++) *(v8bf*)&As[ar][acb + 8 * u] = pa[u];
#pragma unroll
            for (int u = 0; u < 2; u++) *(v8bf*)&Bs[br][bcb + 8 * u] = pb[u];
        }
    }

    if (bn < 1024) {          // ---- Q region: RoPE + QSCALE ----
#pragma unroll
        for (int mf = 0; mf < 4; mf++) {
            int pos_[4];
#pragma unroll
            for (int r = 0; r < 4; r++) pos_[r] = tp[bm + wm + mf * 16 + quad * 4 + r];
#pragma unroll
            for (int nf = 0; nf < 2; nf++) {
                const int col = bn + wn + nf * 16 + l16;
                float fr = __expf(-(float)((col & 63) & ~1) * LN1E4_64);
#pragma unroll
                for (int r = 0; r < 4; r++) {
                    float v = acc[mf][nf][r];
                    float sn, cs;
                    __sincosf((float)pos_[r] * fr, &sn, &cs);
                    float p = __shfl_xor(v, 1);
                    float res = (l16 & 1) ? (p * sn + v * cs) : (v * cs - p * sn);
                    int row = bm + wm + mf * 16 + quad * 4 + r;
                    Qb[(size_t)row * DMODEL + col] = (bf16)(res * QSCALE);
                }
            }
        }
    } else if (bn < 1280) {   // ---- K region: RoPE ----
#pragma unroll
        for (int mf = 0; mf < 4; mf++) {
            int pos_[4];
#pragma unroll
            for (int r = 0; r < 4; r++) pos_[r] = tp[bm + wm + mf * 16 + quad * 4 + r];
#pragma unroll
            for (int nf = 0; nf < 2; nf++) {
                const int kcol = bn - 1024 + wn + nf * 16 + l16;
                float fr = __expf(-(float)((kcol & 63) & ~1) * LN1E4_64);
#pragma unroll
                for (int r = 0; r < 4; r++) {
                    float v = acc[mf][nf][r];
                    float sn, cs;
                    __sincosf((float)pos_[r] * fr, &sn, &cs);
                    float p = __shfl_xor(v, 1);
                    float res = (l16 & 1) ? (p * sn + v * cs) : (v * cs - p * sn);
                    int row = bm + wm + mf * 16 + quad * 4 + r;
                    Kb[(size_t)row * 256 + kcol] = (bf16)res;
                }
            }
        }
    } else {                  // ---- V region: transposed store ----
#pragma unroll
        for (int mf = 0; mf < 4; mf++)
#pragma unroll
            for (int nf = 0; nf < 2; nf++) {
                v4bf pk;
#pragma unroll
                for (int r = 0; r < 4; r++) pk[r] = (bf16)acc[mf][nf][r];
                int vcol = bn - 1280 + wn + nf * 16 + l16;
                int row = bm + wm + mf * 16 + quad * 4;
                *(v4bf*)&Vtg[(size_t)vcol * L_SEQ + row] = pk;
            }
    }
}

// ---------------------------------------------------------------------------
// Output projection: 128x64 tiles, 256 threads. Grid (16, 32) = 512 blocks.
// ---------------------------------------------------------------------------
__global__ __launch_bounds__(256) void gemm_out(const bf16* __restrict__ A,
                                                const bf16* __restrict__ W,
                                                float* __restrict__ C) {
    __shared__ bf16 As[128][68];
    __shared__ bf16 Bs[64][68];
    const int K = 1024, N = 1024;
    const int tid = threadIdx.x;
    const int w = tid >> 6, lane = tid & 63;
    const int quad = lane >> 4, l16 = lane & 15;
    const int wm = (w & 1) * 64, wn = (w >> 1) * 32;
    const int bm = blockIdx.y * 128, bn = blockIdx.x * 64;

    f32x4 acc[4][2];
#pragma unroll
    for (int mf = 0; mf < 4; mf++)
#pragma unroll
        for (int nf = 0; nf < 2; nf++) acc[mf][nf] = (f32x4){0.f, 0.f, 0.f, 0.f};

    const int ar = tid >> 1, acb = (tid & 1) * 32;
    const int br = tid >> 2, bcb = (tid & 3) * 16;

    v8bf pa[4], pb[2];
    {
        const bf16* ap = &A[(size_t)(bm + ar) * K + acb];
        const bf16* bp = &W[(size_t)(bn + br) * K + bcb];
#pragma unroll
        for (int u = 0; u < 4; u++) pa[u] = *(const v8bf*)&ap[8 * u];
#pragma unroll
        for (int u = 0; u < 2; u++) pb[u] = *(const v8bf*)&bp[8 * u];
#pragma unroll
        for (int u = 0; u < 4; u++) *(v8bf*)&As[ar][acb + 8 * u] = pa[u];
#pragma unroll
        for (int u = 0; u < 2; u++) *(v8bf*)&Bs[br][bcb + 8 * u] = pb[u];
    }

    for (int kt = 0; kt < K; kt += 64) {
        __syncthreads();
        const bool more = (kt + 64) < K;
        if (more) {
            const bf16* ap = &A[(size_t)(bm + ar) * K + kt + 64 + acb];
            const bf16* bp = &W[(size_t)(bn + br) * K + kt + 64 + bcb];
#pragma unroll
            for (int u = 0; u < 4; u++) pa[u] = *(const v8bf*)&ap[8 * u];
#pragma unroll
            for (int u = 0; u < 2; u++) pb[u] = *(const v8bf*)&bp[8 * u];
        }
#pragma unroll
        for (int kf = 0; kf < 2; kf++) {
            v8bf a[4], b[2];
#pragma unroll
            for (int mf = 0; mf < 4; mf++) a[mf] = *(v8bf*)&As[wm + mf * 16 + l16][kf * 32 + quad * 8];
#pragma unroll
            for (int nf = 0; nf < 2; nf++) b[nf] = *(v8bf*)&Bs[wn + nf * 16 + l16][kf * 32 + quad * 8];
#pragma unroll
            for (int mf = 0; mf < 4; mf++)
#pragma unroll
                for (int nf = 0; nf < 2; nf++)
                    acc[mf][nf] = __builtin_amdgcn_mfma_f32_16x16x32_bf16(a[mf], b[nf], acc[mf][nf], 0, 0, 0);
        }
        __syncthreads();
        if (more) {
#pragma unroll
            for (int u = 0; u < 4; u++) *(v8bf*)&As[ar][acb + 8 * u] = pa[u];
#pragma unroll
            for (int u = 0; u < 2; u++) *(v8bf*)&Bs[br][bcb + 8 * u] = pb[u];
        }
    }
#pragma unroll
    for (int mf = 0; mf < 4; mf++)
#pragma unroll
        for (int nf = 0; nf < 2; nf++)
#pragma unroll
            for (int r = 0; r < 4; r++) {
                int row = bm + wm + mf * 16 + quad * 4 + r;
                int col = bn + wn + nf * 16 + l16;
                C[(size_t)row * N + col] = acc[mf][nf][r];
            }
}

// ---------------------------------------------------------------------------
// Flash v8: 512 threads (8 waves x 16 q-rows), BQ=128, BK=128, 4-way split-K.
// Halved per-wave register footprint vs 256-thread version: s[8]=32 regs,
// fits launch_bounds(512,4)'s 128-reg budget with NO spills (rounds 10-12
// showed the 32-row wave spills at any 3-blocks/CU budget). 16 waves/CU.
// Ps is wave-private rows -> no extra barriers; 2 barriers/step.
// ---------------------------------------------------------------------------
__global__ __launch_bounds__(512, 4) void flash8(const bf16* __restrict__ Q,
                                                 const bf16* __restrict__ Kb,
                                                 const bf16* __restrict__ Vtg,
                                                 bf16* __restrict__ O0,
                                                 bf16* __restrict__ O1,
                                                 bf16* __restrict__ O2,
                                                 bf16* __restrict__ O3,
                                                 float* __restrict__ ML) {
    __shared__ bf16 Ks[128][68];
    __shared__ bf16 Vt[64][132];
    __shared__ bf16 Ps[128][68];
    const int h = blockIdx.y, kvh = h >> 2;
    const int bx = blockIdx.x;
    const int tid = threadIdx.x;
    const int w = tid >> 6, lane = tid & 63;
    const int quad = lane >> 4, l16 = lane & 15;
    const int krow = tid >> 2, kcb = (tid & 3) * 16;   // K: 128 rows x 64, 2 v8bf/thread
    const int vr = tid >> 3, vcb = (tid & 7) * 16;     // V^T: 64 rows x 128, 2 v8bf/thread
    bf16* const Ops[4] = {O0, O1, O2, O3};

    const int q0 = bx >> 1, i0 = bx & 1;

    for (int p = 0; p < 2; p++) {
        const int qb = p ? (31 - q0) : q0;
        const int j  = p ? (3 - i0) : i0;
        const int T = qb + 1;
        const int k0 = (j * T) >> 2;
        const int k1 = ((j + 1) * T) >> 2;
        bf16* Op = Ops[j];
        float* mlp = ML + (size_t)(j * NHEADS + h) * L_SEQ * 2;

        if (k0 >= k1) {   // empty piece: zero partial (block-uniform)
            for (int idx = tid; idx < 128 * 64; idx += 512) {
                int rr = idx >> 6, cc = idx & 63;
                Op[(size_t)(qb * 128 + rr) * DMODEL + h * DH + cc] = (bf16)0.f;
            }
            if (tid < 128) {
                mlp[(qb * 128 + tid) * 2 + 0] = NEG_BIG;
                mlp[(qb * 128 + tid) * 2 + 1] = 0.f;
            }
            continue;
        }

        // Q fragments: wave w owns rows qb*128 + w*16 + l16
        v8bf qf0 = *(const v8bf*)&Q[(size_t)(qb * 128 + w * 16 + l16) * DMODEL + h * DH + quad * 8];
        v8bf qf1 = *(const v8bf*)&Q[(size_t)(qb * 128 + w * 16 + l16) * DMODEL + h * DH + 32 + quad * 8];

        f32x4 oacc[4];
#pragma unroll
        for (int d = 0; d < 4; d++) oacc[d] = (f32x4){0.f, 0.f, 0.f, 0.f};
        float m_i[4], l_i[4];
#pragma unroll
        for (int r = 0; r < 4; r++) { m_i[r] = NEG_BIG; l_i[r] = 0.f; }

        for (int kb = k0; kb < k1; kb++) {
            __syncthreads();   // prior step's Ks/Vt reads complete
            {   // stage K and V^T directly global -> LDS (coalesced)
                const bf16* ks = &Kb[(size_t)(kb * 128 + krow) * 256 + kvh * DH + kcb];
                const bf16* vs = &Vtg[(size_t)(kvh * DH + vr) * L_SEQ + kb * 128 + vcb];
                *(v8bf*)&Ks[krow][kcb]     = *(const v8bf*)&ks[0];
                *(v8bf*)&Ks[krow][kcb + 8] = *(const v8bf*)&ks[8];
                *(v8bf*)&Vt[vr][vcb]       = *(const v8bf*)&vs[0];
                *(v8bf*)&Vt[vr][vcb + 8]   = *(const v8bf*)&vs[8];
            }
            __syncthreads();   // staged tile visible

            // ---- S = Q K^T : 16 rows x 128 keys (8 n-tiles x 2 k-frags)
            f32x4 s[8];
#pragma unroll
            for (int n = 0; n < 8; n++) {
                v8bf b0 = *(v8bf*)&Ks[n * 16 + l16][quad * 8];
                v8bf b1 = *(v8bf*)&Ks[n * 16 + l16][32 + quad * 8];
                s[n] = (f32x4){0.f, 0.f, 0.f, 0.f};
                s[n] = __builtin_amdgcn_mfma_f32_16x16x32_bf16(qf0, b0, s[n], 0, 0, 0);
                s[n] = __builtin_amdgcn_mfma_f32_16x16x32_bf16(qf1, b1, s[n], 0, 0, 0);
            }

            if (kb == qb) {   // causal mask (diagonal tile only)
                const int rbase = qb * 128 + w * 16 + quad * 4;
#pragma unroll
                for (int n = 0; n < 8; n++) {
                    int colg = kb * 128 + n * 16 + l16;
#pragma unroll
                    for (int r = 0; r < 4; r++)
                        s[n][r] = (colg <= rbase + r) ? s[n][r] : NEG_BIG;
                }
            }

            // ---- online softmax (exp2 domain)
            float mx[4];
#pragma unroll
            for (int r = 0; r < 4; r++) {
                float m0 = s[0][r];
#pragma unroll
                for (int n = 1; n < 8; n++) m0 = fmaxf(m0, s[n][r]);
                mx[r] = m0;
            }
#pragma unroll
            for (int off = 1; off < 16; off <<= 1)
#pragma unroll
                for (int r = 0; r < 4; r++) mx[r] = fmaxf(mx[r], __shfl_xor(mx[r], off));

            float alpha[4], mnew[4], rs[4];
#pragma unroll
            for (int r = 0; r < 4; r++) {
                mnew[r]  = fmaxf(m_i[r], mx[r]);
                alpha[r] = fast_exp2(m_i[r] - mnew[r]);
                rs[r] = 0.f;
            }
#pragma unroll
            for (int n = 0; n < 8; n++)
#pragma unroll
                for (int r = 0; r < 4; r++) {
                    float pv = fast_exp2(s[n][r] - mnew[r]);
                    s[n][r] = pv;
                    rs[r] += pv;
                }
#pragma unroll
            for (int off = 1; off < 16; off <<= 1)
#pragma unroll
                for (int r = 0; r < 4; r++) rs[r] += __shfl_xor(rs[r], off);
#pragma unroll
            for (int r = 0; r < 4; r++) {
                l_i[r] = l_i[r] * alpha[r] + rs[r];
                m_i[r] = mnew[r];
            }
#pragma unroll
            for (int d = 0; d < 4; d++)
#pragma unroll
                for (int r = 0; r < 4; r++) oacc[d][r] *= alpha[r];

            // ---- PV in two 64-key halves; Ps rows [w*16,+16) wave-private
#pragma unroll
            for (int half = 0; half < 2; half++) {
#pragma unroll
                for (int n = 0; n < 4; n++)
#pragma unroll
                    for (int r = 0; r < 4; r++)
                        Ps[w * 16 + quad * 4 + r][n * 16 + l16] = (bf16)s[half * 4 + n][r];
#pragma unroll
                for (int kf = 0; kf < 2; kf++) {
                    v8bf pa = *(v8bf*)&Ps[w * 16 + l16][kf * 32 + quad * 8];
#pragma unroll
                    for (int d = 0; d < 4; d++) {
                        v8bf vb = *(v8bf*)&Vt[d * 16 + l16][half * 64 + kf * 32 + quad * 8];
                        oacc[d] = __builtin_amdgcn_mfma_f32_16x16x32_bf16(pa, vb, oacc[d], 0, 0, 0);
                    }
                }
            }
        }

        // ---- unnormalized partial write
#pragma unroll
        for (int d = 0; d < 4; d++)
#pragma unroll
            for (int r = 0; r < 4; r++) {
                int row = qb * 128 + w * 16 + quad * 4 + r;
                Op[(size_t)row * DMODEL + h * DH + d * 16 + l16] = (bf16)oacc[d][r];
            }
        if (l16 == 0 && quad == 0) {
#pragma unroll
            for (int r = 0; r < 4; r++) {
                int row = qb * 128 + w * 16 + r;   // quad==0 -> rows w*16..w*16+3
                ;
            }
        }
        if (l16 == 0) {
#pragma unroll
            for (int r = 0; r < 4; r++) {
                int row = qb * 128 + w * 16 + quad * 4 + r;
                mlp[row * 2 + 0] = m_i[r];
                mlp[row * 2 + 1] = l_i[r];
            }
        }
    }
}

// ---------------------------------------------------------------------------
// Combine 4 split-K partials into normalized Attn (bf16). exp2 domain.
// ---------------------------------------------------------------------------
__global__ void combine4(const bf16* __restrict__ O0, const bf16* __restrict__ O1,
                         const bf16* __restrict__ O2, const bf16* __restrict__ O3,
                         const float* __restrict__ ML, bf16* __restrict__ Attn) {
    int gid = blockIdx.x * 256 + threadIdx.x;
    int row = gid >> 8;
    int cg = (gid & 255) * 4;
    int h = cg >> 6;
    float m[4], l[4];
#pragma unroll
    for (int j = 0; j < 4; j++) {
        const float* ml = ML + (((size_t)(j * NHEADS + h) * L_SEQ) + row) * 2;
        m[j] = ml[0]; l[j] = ml[1];
    }
    float mmax = fmaxf(fmaxf(m[0], m[1]), fmaxf(m[2], m[3]));
    float a[4], denom = 0.f;
#pragma unroll
    for (int j = 0; j < 4; j++) { a[j] = fast_exp2(m[j] - mmax); denom += a[j] * l[j]; }
    float inv = 1.f / denom;
    v4bf o0 = *(const v4bf*)&O0[(size_t)row * DMODEL + cg];
    v4bf o1 = *(const v4bf*)&O1[(size_t)row * DMODEL + cg];
    v4bf o2 = *(const v4bf*)&O2[(size_t)row * DMODEL + cg];
    v4bf o3 = *(const v4bf*)&O3[(size_t)row * DMODEL + cg];
    v4bf res;
#pragma unroll
    for (int jj = 0; jj < 4; jj++)
        res[jj] = (bf16)((a[0] * (float)o0[jj] + a[1] * (float)o1[jj] +
                          a[2] * (float)o2[jj] + a[3] * (float)o3[jj]) * inv);
    *(v4bf*)&Attn[(size_t)row * DMODEL + cg] = res;
}

// ---------------------------------------------------------------------------
extern "C" void kernel_launch(void* const* d_in, const int* in_sizes, int n_in,
                              void* d_out, int out_size, void* d_ws, size_t ws_size,
                              hipStream_t stream) {
    const float* x  = (const float*)d_in[0];
    const float* Wq = (const float*)d_in[1];
    const float* Wk = (const float*)d_in[2];
    const float* Wv = (const float*)d_in[3];
    const float* Wo = (const float*)d_in[4];
    const int*   tp = (const int*)d_in[5];
    float* out = (float*)d_out;

    bf16*  xb    = (bf16*)d_ws;               // 4,194,304 (reused as Attn)
    bf16*  wqkvb = xb    + 4194304;           // 1,572,864
    bf16*  wob   = wqkvb + 1572864;           // 1,048,576
    bf16*  Qb    = wob   + 1048576;           // 4,194,304
    bf16*  Kb    = Qb    + 4194304;           // 1,048,576  [4096][256]
    bf16*  Vtg   = Kb    + 1048576;           // 1,048,576  [256][4096]
    bf16*  O2    = Vtg   + 1048576;           // 4,194,304 partial j=2
    bf16*  O3    = O2    + 4194304;           // 4,194,304 partial j=3
    float* MLf   = (float*)(O3 + 4194304);    // 524,288 f32
    bf16*  Attn  = xb;
    bf16*  O0    = (bf16*)d_out;              // partial j=0 (in f32 out buffer)
    bf16*  O1    = O0 + 4194304;              // partial j=1

    convert_all<<<6656, 256, 0, stream>>>(x, Wq, Wk, Wv, Wo, xb, wqkvb, wob);
    gemm_qkv<<<dim3(24, 32), 256, 0, stream>>>(xb, wqkvb, Qb, Kb, Vtg, tp);
    flash8<<<dim3(64, NHEADS), 512, 0, stream>>>(Qb, Kb, Vtg, O0, O1, O2, O3, MLf);
    combine4<<<4096, 256, 0, stream>>>(O0, O1, O2, O3, MLf, Attn);
    gemm_out<<<dim3(16, 32), 256, 0, stream>>>(Attn, wob, out);
}